// Round 12
// baseline (2200.551 us; speedup 1.0000x reference)
//
#include <hip/hip_runtime.h>
#include <math.h>
#include <stdint.h>

#define NR_ 16384
#define NP2_ 40000
#define NM_ 30000
#define NE_ 200000
#define EMB_ 1024
#define HID_ 256
#define OUTD_ 128

typedef __attribute__((ext_vector_type(8))) short bf16x8;
typedef __attribute__((ext_vector_type(4))) float f32x4;
typedef __attribute__((ext_vector_type(8))) unsigned short us8;

__device__ __forceinline__ unsigned short f2bf(float f) {
    uint32_t u = __builtin_bit_cast(uint32_t, f);
    u = (u + 0x7FFFu + ((u >> 16) & 1u)) >> 16;
    return (unsigned short)u;
}
__device__ __forceinline__ float bf2f(unsigned short u) {
    uint32_t v = ((uint32_t)u) << 16;
    return __builtin_bit_cast(float, v);
}

// ---------------- batched CSR build ----------------
struct Csr4 {
    const int* src[4]; const int* dst[4];
    int* offs[4]; int* cur[4]; int* csr[4];
    int n[4];
};
__global__ void k_zero4(Csr4 c) {
    int y = blockIdx.y;
    int i = blockIdx.x * 256 + threadIdx.x;
    if (i < c.n[y]) c.cur[y][i] = 0;
}
__global__ void k_deg4(Csr4 c) {
    int y = blockIdx.y;
    int i = blockIdx.x * 256 + threadIdx.x;
    if (i < NE_) atomicAdd(&c.cur[y][c.dst[y][i]], 1);
}
__global__ void k_scanA(Csr4 c, int* __restrict__ csum) {
    int y = blockIdx.y;
    int n = c.n[y];
    int ch = blockIdx.x;
    int nch = (n + 1023) >> 10;
    if (ch >= nch) return;
    const int* deg = c.cur[y];
    int* offs = c.offs[y];
    __shared__ int ts[256];
    int base = ch << 10;
    int t = threadIdx.x;
    int v[4];
    int s = 0;
    #pragma unroll
    for (int k = 0; k < 4; ++k) {
        int i = base + t * 4 + k;
        v[k] = (i < n) ? deg[i] : 0;
        s += v[k];
    }
    ts[t] = s;
    __syncthreads();
    for (int st = 1; st < 256; st <<= 1) {
        int x = ts[t];
        int xo = (t >= st) ? ts[t - st] : 0;
        __syncthreads();
        ts[t] = x + xo;
        __syncthreads();
    }
    int run = (t > 0) ? ts[t - 1] : 0;
    #pragma unroll
    for (int k = 0; k < 4; ++k) {
        int i = base + t * 4 + k;
        if (i < n) offs[i] = run;
        run += v[k];
    }
    if (t == 255) csum[y * 40 + ch] = ts[255];
}
__global__ void k_scanB(Csr4 c, int* __restrict__ csum) {
    int y = threadIdx.x;
    if (y < 4) {
        int n = c.n[y];
        int nch = (n + 1023) >> 10;
        int acc = 0;
        for (int i = 0; i < nch; ++i) {
            int v = csum[y * 40 + i];
            csum[y * 40 + i] = acc;
            acc += v;
        }
        c.offs[y][n] = acc;
    }
}
__global__ void k_scanC(Csr4 c, const int* __restrict__ csum) {
    int y = blockIdx.y;
    int i = blockIdx.x * 256 + threadIdx.x;
    if (i < c.n[y]) {
        int v = c.offs[y][i] + csum[y * 40 + (i >> 10)];
        c.offs[y][i] = v;
        c.cur[y][i] = v;
    }
}
__global__ void k_scatter4(Csr4 c) {
    int y = blockIdx.y;
    int i = blockIdx.x * 256 + threadIdx.x;
    if (i < NE_) {
        int d = c.dst[y][i];
        int p = atomicAdd(&c.cur[y][d], 1);
        c.csr[y][p] = c.src[y][i];
    }
}

// batched weight transpose+convert: dst[n*K+k] = bf16(a[k*N+n] (+ b[k*N+n]))
struct WItem { const float* a; const float* b; unsigned short* dst; int k; int n; };
struct WBatch { WItem it[32]; };
__global__ void k_wconvT(WBatch wb) {
    WItem w = wb.it[blockIdx.y];
    int total = w.k * w.n;
    int kmask = w.k - 1;
    int shift = (w.k == 1024) ? 10 : 8;
    for (int idx = blockIdx.x * 256 + threadIdx.x; idx < total; idx += gridDim.x * 256) {
        int k = idx & kmask, n = idx >> shift;
        float v = w.a[(size_t)k * w.n + n];
        if (w.b) v += w.b[(size_t)k * w.n + n];
        w.dst[idx] = f2bf(v);
    }
}

struct GSeg {
    const void* A; const unsigned short* Bt; void* C; const float* bias;
    int lda, ldc, M, K, ntn, blk0;
};
struct GBatch { GSeg s[3]; int b1, b2, tot; };

// ---------------- batched MFMA GEMM: 256x128 tile, 8 waves (512 thr) ----------------
// Round-8-proven single-buffer 2-barrier schedule, bigger tile:
//   LDS = A 256x64 (32KB) + B 128x64 (16KB) = 48KB -> 3 blocks/CU = 24 waves/CU.
//   1.5x more MFMA per staged byte than 128x128; half the per-block prologue/epilogue.
// AF32: A is f32, reg-staged + converted to bf16 during LDS write.
// Operand-swapped MFMA: D = mfma(bfr, af) -> lane holds 4 consecutive C cols.
template <bool OBF, bool AF32>
__global__ __launch_bounds__(512, 6) void k_gemmb(GBatch gb) {
    __shared__ __align__(16) unsigned short As[256 * 64];
    __shared__ __align__(16) unsigned short Bs[128 * 64];
    const int tid = threadIdx.x;
    const int lane = tid & 63;
    // ---- bijective XCD-chunk swizzle over the merged grid ----
    int nwg = gb.tot;
    int o = blockIdx.x;
    int q = nwg >> 3, r = nwg & 7;
    int xcd = o & 7, j = o >> 3;
    int wg = (xcd < r ? xcd * (q + 1) : r * (q + 1) + (xcd - r) * q) + j;
    const int si = (wg >= gb.b1) + (wg >= gb.b2);
    const GSeg sg = gb.s[si];
    const int local = wg - sg.blk0;
    const int bm = (local / sg.ntn) * 256;
    const int bn = (local % sg.ntn) * 128;
    const int lda = sg.lda, ldc = sg.ldc, M = sg.M, K = sg.K;
    const unsigned short* __restrict__ Bt = sg.Bt;
    const float* __restrict__ bias = sg.bias;

    const int wave = tid >> 6;             // 0..7
    const int wr = (wave >> 1) * 64;       // 0,64,128,192
    const int wc = (wave & 1) * 64;        // 0,64
    const int frow = lane & 15;
    const int fkc = lane >> 4;
    f32x4 acc[4][4] = {};

    for (int k0 = 0; k0 < K; k0 += 64) {
        // ---- stage A: 2048 chunks (16B), 4 per thread ----
        #pragma unroll
        for (int i = 0; i < 4; ++i) {
            int c = tid + i * 512;
            int row = c >> 3, kc = c & 7;
            int srck = k0 + ((kc ^ (row & 7)) << 3);
            int ga = min(bm + row, M - 1);
            if constexpr (AF32) {
                const float* Af = (const float*)sg.A + (size_t)ga * lda + srck;
                float4 a0 = *(const float4*)Af;
                float4 a1 = *(const float4*)(Af + 4);
                us8 oo;
                oo[0] = f2bf(a0.x); oo[1] = f2bf(a0.y); oo[2] = f2bf(a0.z); oo[3] = f2bf(a0.w);
                oo[4] = f2bf(a1.x); oo[5] = f2bf(a1.y); oo[6] = f2bf(a1.z); oo[7] = f2bf(a1.w);
                *(us8*)(As + (size_t)c * 8) = oo;
            } else {
                __builtin_amdgcn_global_load_lds(
                    (const __attribute__((address_space(1))) unsigned int*)((const unsigned short*)sg.A + (size_t)ga * lda + srck),
                    (__attribute__((address_space(3))) unsigned int*)(As + (size_t)c * 8), 16, 0, 0);
            }
        }
        // ---- stage B: 1024 chunks, 2 per thread ----
        #pragma unroll
        for (int i = 0; i < 2; ++i) {
            int c = tid + i * 512;
            int row = c >> 3, kc = c & 7;
            int srck = k0 + ((kc ^ (row & 7)) << 3);
            __builtin_amdgcn_global_load_lds(
                (const __attribute__((address_space(1))) unsigned int*)(Bt + (size_t)(bn + row) * K + srck),
                (__attribute__((address_space(3))) unsigned int*)(Bs + (size_t)c * 8), 16, 0, 0);
        }
        __syncthreads();
        #pragma unroll
        for (int kk = 0; kk < 2; ++kk) {
            bf16x8 af[4], bfr[4];
            #pragma unroll
            for (int m = 0; m < 4; ++m) {
                int row = wr + m * 16 + frow;
                int kc = kk * 4 + fkc;
                af[m] = *(const bf16x8*)(As + (size_t)((row << 3) + (kc ^ (row & 7))) * 8);
            }
            #pragma unroll
            for (int n = 0; n < 4; ++n) {
                int row = wc + n * 16 + frow;
                int kc = kk * 4 + fkc;
                bfr[n] = *(const bf16x8*)(Bs + (size_t)((row << 3) + (kc ^ (row & 7))) * 8);
            }
            #pragma unroll
            for (int m = 0; m < 4; ++m)
                #pragma unroll
                for (int n = 0; n < 4; ++n)
                    acc[m][n] = __builtin_amdgcn_mfma_f32_16x16x32_bf16(bfr[n], af[m], acc[m][n], 0, 0, 0);
        }
        __syncthreads();
    }

    // D = Bt_tile · A_tile^T: X-dim (lane>>4, reg) = C col, Y-dim (lane&15) = C row
    const int ccol0 = (lane >> 4) << 2;
    #pragma unroll
    for (int m = 0; m < 4; ++m) {
        int row = bm + wr + m * 16 + frow;
        if (row < M) {
            #pragma unroll
            for (int n = 0; n < 4; ++n) {
                int col = bn + wc + n * 16 + ccol0;
                f32x4 v = acc[m][n];
                if (bias) {
                    v[0] += bias[col + 0];
                    v[1] += bias[col + 1];
                    v[2] += bias[col + 2];
                    v[3] += bias[col + 3];
                }
                if constexpr (OBF) {
                    ushort4 oo;
                    oo.x = f2bf(v[0]); oo.y = f2bf(v[1]); oo.z = f2bf(v[2]); oo.w = f2bf(v[3]);
                    *(ushort4*)((unsigned short*)sg.C + (size_t)row * ldc + col) = oo;
                } else {
                    *(float4*)((float*)sg.C + (size_t)row * ldc + col) = make_float4(v[0], v[1], v[2], v[3]);
                }
            }
        }
    }
}

// ---------------- merged wave-per-node CSR mean-aggregate (bf16 RMW), 3 segments ----------------
struct ASeg {
    const int* offsA; const int* csrA; const unsigned short* projA; int ldpA; const float* biasA;
    const int* offsB; const int* csrB; const unsigned short* projB; int ldpB; const float* biasB;
    unsigned short* outx; int ldo; int ndst; int blk0;
};
struct ABatch { ASeg s[3]; int b1, b2; };

__global__ __launch_bounds__(256) void k_aggb(ABatch ab) {
    int b = blockIdx.x;
    int si = (b >= ab.b1) + (b >= ab.b2);
    const ASeg sg = ab.s[si];
    int node = (b - sg.blk0) * 4 + (threadIdx.x >> 6);
    int lane = threadIdx.x & 63;
    if (node >= sg.ndst) return;

    float a0 = 0.f, a1 = 0.f, a2 = 0.f, a3 = 0.f;
    int begA = sg.offsA[node], endA = sg.offsA[node + 1];
    {
        const unsigned short* baseA = sg.projA + lane * 4;
        const int* csrA = sg.csrA;
        int ldpA = sg.ldpA;
        int e = begA;
        for (; e + 3 < endA; e += 4) {
            int i0 = csrA[e], i1 = csrA[e + 1], i2 = csrA[e + 2], i3 = csrA[e + 3];
            ushort4 u0 = *(const ushort4*)(baseA + (size_t)i0 * ldpA);
            ushort4 u1 = *(const ushort4*)(baseA + (size_t)i1 * ldpA);
            ushort4 u2 = *(const ushort4*)(baseA + (size_t)i2 * ldpA);
            ushort4 u3 = *(const ushort4*)(baseA + (size_t)i3 * ldpA);
            a0 += bf2f(u0.x) + bf2f(u1.x) + bf2f(u2.x) + bf2f(u3.x);
            a1 += bf2f(u0.y) + bf2f(u1.y) + bf2f(u2.y) + bf2f(u3.y);
            a2 += bf2f(u0.z) + bf2f(u1.z) + bf2f(u2.z) + bf2f(u3.z);
            a3 += bf2f(u0.w) + bf2f(u1.w) + bf2f(u2.w) + bf2f(u3.w);
        }
        for (; e < endA; ++e) {
            ushort4 u = *(const ushort4*)(baseA + (size_t)csrA[e] * ldpA);
            a0 += bf2f(u.x); a1 += bf2f(u.y); a2 += bf2f(u.z); a3 += bf2f(u.w);
        }
    }
    float invA = 1.f / fmaxf((float)(endA - begA), 1.f);
    float4 bA = ((const float4*)sg.biasA)[lane];
    float r0 = a0 * invA + bA.x;
    float r1 = a1 * invA + bA.y;
    float r2 = a2 * invA + bA.z;
    float r3 = a3 * invA + bA.w;

    if (sg.csrB) {
        float b0 = 0.f, b1 = 0.f, b2 = 0.f, b3 = 0.f;
        int begB = sg.offsB[node], endB = sg.offsB[node + 1];
        const unsigned short* baseB = sg.projB + lane * 4;
        const int* csrB = sg.csrB;
        int ldpB = sg.ldpB;
        int e = begB;
        for (; e + 3 < endB; e += 4) {
            int i0 = csrB[e], i1 = csrB[e + 1], i2 = csrB[e + 2], i3 = csrB[e + 3];
            ushort4 u0 = *(const ushort4*)(baseB + (size_t)i0 * ldpB);
            ushort4 u1 = *(const ushort4*)(baseB + (size_t)i1 * ldpB);
            ushort4 u2 = *(const ushort4*)(baseB + (size_t)i2 * ldpB);
            ushort4 u3 = *(const ushort4*)(baseB + (size_t)i3 * ldpB);
            b0 += bf2f(u0.x) + bf2f(u1.x) + bf2f(u2.x) + bf2f(u3.x);
            b1 += bf2f(u0.y) + bf2f(u1.y) + bf2f(u2.y) + bf2f(u3.y);
            b2 += bf2f(u0.z) + bf2f(u1.z) + bf2f(u2.z) + bf2f(u3.z);
            b3 += bf2f(u0.w) + bf2f(u1.w) + bf2f(u2.w) + bf2f(u3.w);
        }
        for (; e < endB; ++e) {
            ushort4 u = *(const ushort4*)(baseB + (size_t)csrB[e] * ldpB);
            b0 += bf2f(u.x); b1 += bf2f(u.y); b2 += bf2f(u.z); b3 += bf2f(u.w);
        }
        float invB = 1.f / fmaxf((float)(endB - begB), 1.f);
        float4 bB = ((const float4*)sg.biasB)[lane];
        r0 += b0 * invB + bB.x;
        r1 += b1 * invB + bB.y;
        r2 += b2 * invB + bB.z;
        r3 += b3 * invB + bB.w;
    }

    size_t o = (size_t)node * sg.ldo + lane * 4;
    ushort4 cur = *(const ushort4*)(sg.outx + o);
    ushort4 w;
    w.x = f2bf(bf2f(cur.x) + r0);
    w.y = f2bf(bf2f(cur.y) + r1);
    w.z = f2bf(bf2f(cur.z) + r2);
    w.w = f2bf(bf2f(cur.w) + r3);
    *(ushort4*)(sg.outx + o) = w;
}

// ---------------- cosine: one wave per row ----------------
__global__ __launch_bounds__(256) void k_cos(const float* __restrict__ ro,
                                             const float* __restrict__ pr,
                                             const int* __restrict__ types,
                                             float* __restrict__ out, int nr) {
    int row = blockIdx.x * 4 + (threadIdx.x >> 6);
    int lane = threadIdx.x & 63;
    if (row >= nr) return;
    int t = types[row];
    float2 r = ((const float2*)(ro + (size_t)row * OUTD_))[lane];
    float2 nn = ((const float2*)(pr + (size_t)row * 384 + t * OUTD_))[lane];
    float num = r.x * nn.x + r.y * nn.y;
    float d1 = r.x * r.x + r.y * r.y;
    float d2 = nn.x * nn.x + nn.y * nn.y;
    #pragma unroll
    for (int s = 1; s < 64; s <<= 1) {
        num += __shfl_xor(num, s);
        d1 += __shfl_xor(d1, s);
        d2 += __shfl_xor(d2, s);
    }
    if (lane == 0) out[row] = (num / fmaxf(sqrtf(d1) * sqrtf(d2), 1e-8f) + 1.f) * 0.5f;
}

extern "C" void kernel_launch(void* const* d_in, const int* in_sizes, int n_in,
                              void* d_out, int out_size, void* d_ws, size_t ws_size,
                              hipStream_t stream) {
    const float* x_r0 = (const float*)d_in[0];
    const float* x_p0 = (const float*)d_in[1];
    const float* x_m0 = (const float*)d_in[2];
    const int* e_src[4] = {(const int*)d_in[3], (const int*)d_in[5], (const int*)d_in[7], (const int*)d_in[9]};
    const int* e_dst[4] = {(const int*)d_in[4], (const int*)d_in[6], (const int*)d_in[8], (const int*)d_in[10]};
    const float* notes = (const float*)d_in[11];
    const int* types = (const int*)d_in[12];
    const float* Wl0 = (const float*)d_in[13];
    const float* Wr0 = (const float*)d_in[14];
    const float* bl0 = (const float*)d_in[15];
    const float* WlL = (const float*)d_in[16];
    const float* WrL = (const float*)d_in[17];
    const float* blL = (const float*)d_in[18];
    const float* Wre = (const float*)d_in[19];
    const float* bre = (const float*)d_in[20];
    const float* Wn  = (const float*)d_in[21];
    const float* bn  = (const float*)d_in[22];
    float* out = (float*)d_out;

    // ---- workspace carve ----
    uintptr_t base = (uintptr_t)d_ws;
    auto alloc = [&](size_t bytes) -> void* {
        uintptr_t p = (base + 255) & ~(uintptr_t)255;
        base = p + bytes;
        return (void*)p;
    };
    unsigned short* Rb[2] = {(unsigned short*)alloc((size_t)NR_ * 768 * 2),
                             (unsigned short*)alloc((size_t)NR_ * 768 * 2)};
    unsigned short* Pb[2] = {(unsigned short*)alloc((size_t)NP2_ * 512 * 2),
                             (unsigned short*)alloc((size_t)NP2_ * 512 * 2)};
    unsigned short* Mb[2] = {(unsigned short*)alloc((size_t)NM_ * 512 * 2),
                             (unsigned short*)alloc((size_t)NM_ * 512 * 2)};
    float* ro = (float*)alloc((size_t)NR_ * OUTD_ * 4);
    float* pr = (float*)alloc((size_t)NR_ * 384 * 4);
    unsigned short* wbf = (unsigned short*)alloc((size_t)4000000 * 2);
    int* csum = (int*)alloc(160 * 4);
    int nd[4] = {NR_, NR_, NP2_, NM_};
    Csr4 cs{};
    for (int t = 0; t < 4; ++t) {
        cs.src[t] = e_src[t]; cs.dst[t] = e_dst[t]; cs.n[t] = nd[t];
        cs.offs[t] = (int*)alloc(((size_t)nd[t] + 1) * 4);
        cs.cur[t]  = (int*)alloc((size_t)nd[t] * 4);
        cs.csr[t]  = (int*)alloc((size_t)NE_ * 4);
    }

    // ---- weight transpose+convert: concatenated B blocks, bf16 [N][K] ----
    unsigned short *BR[4], *BP[4], *BM[4], *Bre, *Bn;
    {
        WBatch wb{};
        int cnt = 0;
        size_t woff = 0;
        auto add = [&](const float* a, const float* bb, int K, int N) -> unsigned short* {
            unsigned short* dst = wbf + woff;
            woff += (size_t)K * N;
            wb.it[cnt] = WItem{a, bb, dst, K, N};
            ++cnt;
            return dst;
        };
        const size_t w0 = (size_t)EMB_ * HID_;
        const size_t wl = (size_t)HID_ * HID_;
        for (int l = 0; l < 4; ++l) {
            int K = (l == 0) ? EMB_ : HID_;
            const float* Wr_ = (l == 0) ? Wr0 : WrL + (size_t)(l - 1) * 4 * wl;
            const float* Wl_ = (l == 0) ? Wl0 : WlL + (size_t)(l - 1) * 4 * wl;
            size_t ws_ = (l == 0) ? w0 : wl;
            BR[l] = add(Wr_ + 0 * ws_, Wr_ + 1 * ws_, K, HID_);  // WrC
            add(Wl_ + 2 * ws_, nullptr, K, HID_);                 // Wl2 (r2p proj)
            add(Wl_ + 3 * ws_, nullptr, K, HID_);                 // Wl3 (r2m proj)
            BP[l] = add(Wr_ + 2 * ws_, nullptr, K, HID_);         // Wr2
            add(Wl_ + 0 * ws_, nullptr, K, HID_);                 // Wl0 (p2r proj)
            BM[l] = add(Wr_ + 3 * ws_, nullptr, K, HID_);         // Wr3
            add(Wl_ + 1 * ws_, nullptr, K, HID_);                 // Wl1 (m2r proj)
        }
        Bre = add(Wre, nullptr, HID_, OUTD_);
        Bn = add(Wn + 0 * (size_t)EMB_ * OUTD_, nullptr, EMB_, OUTD_);
        add(Wn + 1 * (size_t)EMB_ * OUTD_, nullptr, EMB_, OUTD_);
        add(Wn + 2 * (size_t)EMB_ * OUTD_, nullptr, EMB_, OUTD_);
        k_wconvT<<<dim3(128, cnt), 256, 0, stream>>>(wb);
    }

    // ---- CSR build (batched over the 4 edge types) ----
    k_zero4<<<dim3((NP2_ + 255) / 256, 4), 256, 0, stream>>>(cs);
    k_deg4<<<dim3((NE_ + 255) / 256, 4), 256, 0, stream>>>(cs);
    k_scanA<<<dim3(40, 4), 256, 0, stream>>>(cs, csum);
    k_scanB<<<1, 64, 0, stream>>>(cs, csum);
    k_scanC<<<dim3((NP2_ + 255) / 256, 4), 256, 0, stream>>>(cs, csum);
    k_scatter4<<<dim3((NE_ + 255) / 256, 4), 256, 0, stream>>>(cs);

    // tile counts at BM=256
    const int MT_R = (NR_ + 255) / 256;    // 64
    const int MT_P = (NP2_ + 255) / 256;   // 157
    const int MT_M = (NM_ + 255) / 256;    // 118
    auto seg = [](const void* A, const unsigned short* Bt, void* C, const float* bias,
                  int lda, int ldc, int M, int K, int ntn, int blk0) -> GSeg {
        return GSeg{A, Bt, C, bias, lda, ldc, M, K, ntn, blk0};
    };

    const int AB_R = (NR_ + 3) / 4, AB_P = (NP2_ + 3) / 4, AB_M = (NM_ + 3) / 4;

    for (int l = 0; l < 4; ++l) {
        int K = (l == 0) ? EMB_ : HID_;
        unsigned short* R = Rb[l & 1];
        unsigned short* P = Pb[l & 1];
        unsigned short* M = Mb[l & 1];
        const float* bl_ = (l == 0) ? bl0 : blL + (size_t)(l - 1) * 4 * HID_;

        GBatch gb{};
        int nR = MT_R * 6, nP = MT_P * 4, nM = MT_M * 4;
        if (l == 0) {
            gb.s[0] = seg(x_r0, BR[0], R, nullptr, EMB_, 768, NR_, EMB_, 6, 0);
            gb.s[1] = seg(x_p0, BP[0], P, nullptr, EMB_, 512, NP2_, EMB_, 4, nR);
            gb.s[2] = seg(x_m0, BM[0], M, nullptr, EMB_, 512, NM_, EMB_, 4, nR + nP);
        } else {
            gb.s[0] = seg(Rb[(l - 1) & 1], BR[l], R, nullptr, 768, 768, NR_, K, 6, 0);
            gb.s[1] = seg(Pb[(l - 1) & 1], BP[l], P, nullptr, 512, 512, NP2_, K, 4, nR);
            gb.s[2] = seg(Mb[(l - 1) & 1], BM[l], M, nullptr, 512, 512, NM_, K, 4, nR + nP);
        }
        gb.b1 = nR; gb.b2 = nR + nP; gb.tot = nR + nP + nM;
        if (l == 0) k_gemmb<true, true><<<gb.tot, 512, 0, stream>>>(gb);
        else        k_gemmb<true, false><<<gb.tot, 512, 0, stream>>>(gb);

        // merged aggregates: reaction (p2r + m2r), protein (r2p), molecule (r2m)
        ABatch ab{};
        ab.s[0] = ASeg{cs.offs[0], cs.csr[0], P + 256, 512, bl_ + 0 * HID_,
                       cs.offs[1], cs.csr[1], M + 256, 512, bl_ + 1 * HID_,
                       R, 768, NR_, 0};
        ab.s[1] = ASeg{cs.offs[2], cs.csr[2], R + 256, 768, bl_ + 2 * HID_,
                       nullptr, nullptr, nullptr, 0, nullptr,
                       P, 512, NP2_, AB_R};
        ab.s[2] = ASeg{cs.offs[3], cs.csr[3], R + 512, 768, bl_ + 3 * HID_,
                       nullptr, nullptr, nullptr, 0, nullptr,
                       M, 512, NM_, AB_R + AB_P};
        ab.b1 = AB_R; ab.b2 = AB_R + AB_P;
        k_aggb<<<AB_R + AB_P + AB_M, 256, 0, stream>>>(ab);
    }

    // ---- finale: reaction proj (bf16-A) + notes projs (f32-A) + cosine ----
    {
        GBatch g1{};
        g1.s[0] = seg(Rb[1], Bre, ro, bre, 768, OUTD_, NR_, HID_, 1, 0);
        g1.b1 = g1.b2 = g1.tot = MT_R;
        k_gemmb<false, false><<<g1.tot, 512, 0, stream>>>(g1);
        GBatch g2{};
        g2.s[0] = seg(notes, Bn, pr, bn, EMB_, 384, NR_, EMB_, 3, 0);
        g2.b1 = g2.b2 = g2.tot = MT_R * 3;
        k_gemmb<false, true><<<g2.tot, 512, 0, stream>>>(g2);
    }
    k_cos<<<NR_ / 4, 256, 0, stream>>>(ro, pr, types, out, NR_);
}

// Round 13
// 837.014 us; speedup vs baseline: 2.6290x; 2.6290x over previous
//
#include <hip/hip_runtime.h>
#include <math.h>
#include <stdint.h>

#define NR_ 16384
#define NP2_ 40000
#define NM_ 30000
#define NE_ 200000
#define EMB_ 1024
#define HID_ 256
#define OUTD_ 128

typedef __attribute__((ext_vector_type(8))) short bf16x8;
typedef __attribute__((ext_vector_type(4))) float f32x4;
typedef __attribute__((ext_vector_type(8))) unsigned short us8;

__device__ __forceinline__ unsigned short f2bf(float f) {
    uint32_t u = __builtin_bit_cast(uint32_t, f);
    u = (u + 0x7FFFu + ((u >> 16) & 1u)) >> 16;
    return (unsigned short)u;
}
__device__ __forceinline__ float bf2f(unsigned short u) {
    uint32_t v = ((uint32_t)u) << 16;
    return __builtin_bit_cast(float, v);
}

// ---------------- batched CSR build ----------------
struct Csr4 {
    const int* src[4]; const int* dst[4];
    int* offs[4]; int* cur[4]; int* csr[4];
    int n[4];
};
__global__ void k_zero4(Csr4 c) {
    int y = blockIdx.y;
    int i = blockIdx.x * 256 + threadIdx.x;
    if (i < c.n[y]) c.cur[y][i] = 0;
}
__global__ void k_deg4(Csr4 c) {
    int y = blockIdx.y;
    int i = blockIdx.x * 256 + threadIdx.x;
    if (i < NE_) atomicAdd(&c.cur[y][c.dst[y][i]], 1);
}
__global__ void k_scanA(Csr4 c, int* __restrict__ csum) {
    int y = blockIdx.y;
    int n = c.n[y];
    int ch = blockIdx.x;
    int nch = (n + 1023) >> 10;
    if (ch >= nch) return;
    const int* deg = c.cur[y];
    int* offs = c.offs[y];
    __shared__ int ts[256];
    int base = ch << 10;
    int t = threadIdx.x;
    int v[4];
    int s = 0;
    #pragma unroll
    for (int k = 0; k < 4; ++k) {
        int i = base + t * 4 + k;
        v[k] = (i < n) ? deg[i] : 0;
        s += v[k];
    }
    ts[t] = s;
    __syncthreads();
    for (int st = 1; st < 256; st <<= 1) {
        int x = ts[t];
        int xo = (t >= st) ? ts[t - st] : 0;
        __syncthreads();
        ts[t] = x + xo;
        __syncthreads();
    }
    int run = (t > 0) ? ts[t - 1] : 0;
    #pragma unroll
    for (int k = 0; k < 4; ++k) {
        int i = base + t * 4 + k;
        if (i < n) offs[i] = run;
        run += v[k];
    }
    if (t == 255) csum[y * 40 + ch] = ts[255];
}
__global__ void k_scanB(Csr4 c, int* __restrict__ csum) {
    int y = threadIdx.x;
    if (y < 4) {
        int n = c.n[y];
        int nch = (n + 1023) >> 10;
        int acc = 0;
        for (int i = 0; i < nch; ++i) {
            int v = csum[y * 40 + i];
            csum[y * 40 + i] = acc;
            acc += v;
        }
        c.offs[y][n] = acc;
    }
}
__global__ void k_scanC(Csr4 c, const int* __restrict__ csum) {
    int y = blockIdx.y;
    int i = blockIdx.x * 256 + threadIdx.x;
    if (i < c.n[y]) {
        int v = c.offs[y][i] + csum[y * 40 + (i >> 10)];
        c.offs[y][i] = v;
        c.cur[y][i] = v;
    }
}
__global__ void k_scatter4(Csr4 c) {
    int y = blockIdx.y;
    int i = blockIdx.x * 256 + threadIdx.x;
    if (i < NE_) {
        int d = c.dst[y][i];
        int p = atomicAdd(&c.cur[y][d], 1);
        c.csr[y][p] = c.src[y][i];
    }
}

// batched weight transpose+convert: dst[n*K+k] = bf16(a[k*N+n] (+ b[k*N+n]))
struct WItem { const float* a; const float* b; unsigned short* dst; int k; int n; };
struct WBatch { WItem it[32]; };
__global__ void k_wconvT(WBatch wb) {
    WItem w = wb.it[blockIdx.y];
    int total = w.k * w.n;
    int kmask = w.k - 1;
    int shift = (w.k == 1024) ? 10 : 8;
    for (int idx = blockIdx.x * 256 + threadIdx.x; idx < total; idx += gridDim.x * 256) {
        int k = idx & kmask, n = idx >> shift;
        float v = w.a[(size_t)k * w.n + n];
        if (w.b) v += w.b[(size_t)k * w.n + n];
        w.dst[idx] = f2bf(v);
    }
}

struct GSeg {
    const void* A; const unsigned short* Bt; void* C; const float* bias;
    int lda, ldc, M, K, ntn, blk0;
};
struct GBatch { GSeg s[3]; int b1, b2, tot; };

// ---------------- batched MFMA GEMM: 256x128 tile, 8 waves (512 thr) ----------------
// Single-buffer 2-barrier schedule (round-8 proven). LDS 48KB -> 3 blocks/CU (LDS-limited)
// = 24 waves/CU. __launch_bounds__(512) ONLY (thread cap): no min-waves arg, so the VGPR
// allocator keeps its natural ~90-110 allocation (round-12 lesson: forcing a cap near the
// natural allocation spills acc[] to scratch -> 10x traffic).
// AF32: A is f32, reg-staged + converted to bf16 during LDS write.
// Operand-swapped MFMA: D = mfma(bfr, af) -> lane holds 4 consecutive C cols.
template <bool OBF, bool AF32>
__global__ __launch_bounds__(512) void k_gemmb(GBatch gb) {
    __shared__ __align__(16) unsigned short As[256 * 64];
    __shared__ __align__(16) unsigned short Bs[128 * 64];
    const int tid = threadIdx.x;
    const int lane = tid & 63;
    // ---- bijective XCD-chunk swizzle over the merged grid ----
    int nwg = gb.tot;
    int o = blockIdx.x;
    int q = nwg >> 3, r = nwg & 7;
    int xcd = o & 7, j = o >> 3;
    int wg = (xcd < r ? xcd * (q + 1) : r * (q + 1) + (xcd - r) * q) + j;
    const int si = (wg >= gb.b1) + (wg >= gb.b2);
    const GSeg sg = gb.s[si];
    const int local = wg - sg.blk0;
    const int bm = (local / sg.ntn) * 256;
    const int bn = (local % sg.ntn) * 128;
    const int lda = sg.lda, ldc = sg.ldc, M = sg.M, K = sg.K;
    const unsigned short* __restrict__ Bt = sg.Bt;
    const float* __restrict__ bias = sg.bias;

    const int wave = tid >> 6;             // 0..7
    const int wr = (wave >> 1) * 64;       // 0,64,128,192
    const int wc = (wave & 1) * 64;        // 0,64
    const int frow = lane & 15;
    const int fkc = lane >> 4;
    f32x4 acc[4][4] = {};

    for (int k0 = 0; k0 < K; k0 += 64) {
        // ---- stage A: 2048 chunks (16B), 4 per thread ----
        #pragma unroll
        for (int i = 0; i < 4; ++i) {
            int c = tid + i * 512;
            int row = c >> 3, kc = c & 7;
            int srck = k0 + ((kc ^ (row & 7)) << 3);
            int ga = min(bm + row, M - 1);
            if constexpr (AF32) {
                const float* Af = (const float*)sg.A + (size_t)ga * lda + srck;
                float4 a0 = *(const float4*)Af;
                float4 a1 = *(const float4*)(Af + 4);
                us8 oo;
                oo[0] = f2bf(a0.x); oo[1] = f2bf(a0.y); oo[2] = f2bf(a0.z); oo[3] = f2bf(a0.w);
                oo[4] = f2bf(a1.x); oo[5] = f2bf(a1.y); oo[6] = f2bf(a1.z); oo[7] = f2bf(a1.w);
                *(us8*)(As + (size_t)c * 8) = oo;
            } else {
                __builtin_amdgcn_global_load_lds(
                    (const __attribute__((address_space(1))) unsigned int*)((const unsigned short*)sg.A + (size_t)ga * lda + srck),
                    (__attribute__((address_space(3))) unsigned int*)(As + (size_t)c * 8), 16, 0, 0);
            }
        }
        // ---- stage B: 1024 chunks, 2 per thread ----
        #pragma unroll
        for (int i = 0; i < 2; ++i) {
            int c = tid + i * 512;
            int row = c >> 3, kc = c & 7;
            int srck = k0 + ((kc ^ (row & 7)) << 3);
            __builtin_amdgcn_global_load_lds(
                (const __attribute__((address_space(1))) unsigned int*)(Bt + (size_t)(bn + row) * K + srck),
                (__attribute__((address_space(3))) unsigned int*)(Bs + (size_t)c * 8), 16, 0, 0);
        }
        __syncthreads();
        #pragma unroll
        for (int kk = 0; kk < 2; ++kk) {
            bf16x8 af[4], bfr[4];
            #pragma unroll
            for (int m = 0; m < 4; ++m) {
                int row = wr + m * 16 + frow;
                int kc = kk * 4 + fkc;
                af[m] = *(const bf16x8*)(As + (size_t)((row << 3) + (kc ^ (row & 7))) * 8);
            }
            #pragma unroll
            for (int n = 0; n < 4; ++n) {
                int row = wc + n * 16 + frow;
                int kc = kk * 4 + fkc;
                bfr[n] = *(const bf16x8*)(Bs + (size_t)((row << 3) + (kc ^ (row & 7))) * 8);
            }
            #pragma unroll
            for (int m = 0; m < 4; ++m)
                #pragma unroll
                for (int n = 0; n < 4; ++n)
                    acc[m][n] = __builtin_amdgcn_mfma_f32_16x16x32_bf16(bfr[n], af[m], acc[m][n], 0, 0, 0);
        }
        __syncthreads();
    }

    // D = Bt_tile · A_tile^T: X-dim (lane>>4, reg) = C col, Y-dim (lane&15) = C row
    const int ccol0 = (lane >> 4) << 2;
    #pragma unroll
    for (int m = 0; m < 4; ++m) {
        int row = bm + wr + m * 16 + frow;
        if (row < M) {
            #pragma unroll
            for (int n = 0; n < 4; ++n) {
                int col = bn + wc + n * 16 + ccol0;
                f32x4 v = acc[m][n];
                if (bias) {
                    v[0] += bias[col + 0];
                    v[1] += bias[col + 1];
                    v[2] += bias[col + 2];
                    v[3] += bias[col + 3];
                }
                if constexpr (OBF) {
                    ushort4 oo;
                    oo.x = f2bf(v[0]); oo.y = f2bf(v[1]); oo.z = f2bf(v[2]); oo.w = f2bf(v[3]);
                    *(ushort4*)((unsigned short*)sg.C + (size_t)row * ldc + col) = oo;
                } else {
                    *(float4*)((float*)sg.C + (size_t)row * ldc + col) = make_float4(v[0], v[1], v[2], v[3]);
                }
            }
        }
    }
}

// ---------------- merged wave-per-node CSR mean-aggregate (bf16 RMW), 3 segments ----------------
struct ASeg {
    const int* offsA; const int* csrA; const unsigned short* projA; int ldpA; const float* biasA;
    const int* offsB; const int* csrB; const unsigned short* projB; int ldpB; const float* biasB;
    unsigned short* outx; int ldo; int ndst; int blk0;
};
struct ABatch { ASeg s[3]; int b1, b2; };

__global__ __launch_bounds__(256) void k_aggb(ABatch ab) {
    int b = blockIdx.x;
    int si = (b >= ab.b1) + (b >= ab.b2);
    const ASeg sg = ab.s[si];
    int node = (b - sg.blk0) * 4 + (threadIdx.x >> 6);
    int lane = threadIdx.x & 63;
    if (node >= sg.ndst) return;

    float a0 = 0.f, a1 = 0.f, a2 = 0.f, a3 = 0.f;
    int begA = sg.offsA[node], endA = sg.offsA[node + 1];
    {
        const unsigned short* baseA = sg.projA + lane * 4;
        const int* csrA = sg.csrA;
        int ldpA = sg.ldpA;
        int e = begA;
        for (; e + 3 < endA; e += 4) {
            int i0 = csrA[e], i1 = csrA[e + 1], i2 = csrA[e + 2], i3 = csrA[e + 3];
            ushort4 u0 = *(const ushort4*)(baseA + (size_t)i0 * ldpA);
            ushort4 u1 = *(const ushort4*)(baseA + (size_t)i1 * ldpA);
            ushort4 u2 = *(const ushort4*)(baseA + (size_t)i2 * ldpA);
            ushort4 u3 = *(const ushort4*)(baseA + (size_t)i3 * ldpA);
            a0 += bf2f(u0.x) + bf2f(u1.x) + bf2f(u2.x) + bf2f(u3.x);
            a1 += bf2f(u0.y) + bf2f(u1.y) + bf2f(u2.y) + bf2f(u3.y);
            a2 += bf2f(u0.z) + bf2f(u1.z) + bf2f(u2.z) + bf2f(u3.z);
            a3 += bf2f(u0.w) + bf2f(u1.w) + bf2f(u2.w) + bf2f(u3.w);
        }
        for (; e < endA; ++e) {
            ushort4 u = *(const ushort4*)(baseA + (size_t)csrA[e] * ldpA);
            a0 += bf2f(u.x); a1 += bf2f(u.y); a2 += bf2f(u.z); a3 += bf2f(u.w);
        }
    }
    float invA = 1.f / fmaxf((float)(endA - begA), 1.f);
    float4 bA = ((const float4*)sg.biasA)[lane];
    float r0 = a0 * invA + bA.x;
    float r1 = a1 * invA + bA.y;
    float r2 = a2 * invA + bA.z;
    float r3 = a3 * invA + bA.w;

    if (sg.csrB) {
        float b0 = 0.f, b1 = 0.f, b2 = 0.f, b3 = 0.f;
        int begB = sg.offsB[node], endB = sg.offsB[node + 1];
        const unsigned short* baseB = sg.projB + lane * 4;
        const int* csrB = sg.csrB;
        int ldpB = sg.ldpB;
        int e = begB;
        for (; e + 3 < endB; e += 4) {
            int i0 = csrB[e], i1 = csrB[e + 1], i2 = csrB[e + 2], i3 = csrB[e + 3];
            ushort4 u0 = *(const ushort4*)(baseB + (size_t)i0 * ldpB);
            ushort4 u1 = *(const ushort4*)(baseB + (size_t)i1 * ldpB);
            ushort4 u2 = *(const ushort4*)(baseB + (size_t)i2 * ldpB);
            ushort4 u3 = *(const ushort4*)(baseB + (size_t)i3 * ldpB);
            b0 += bf2f(u0.x) + bf2f(u1.x) + bf2f(u2.x) + bf2f(u3.x);
            b1 += bf2f(u0.y) + bf2f(u1.y) + bf2f(u2.y) + bf2f(u3.y);
            b2 += bf2f(u0.z) + bf2f(u1.z) + bf2f(u2.z) + bf2f(u3.z);
            b3 += bf2f(u0.w) + bf2f(u1.w) + bf2f(u2.w) + bf2f(u3.w);
        }
        for (; e < endB; ++e) {
            ushort4 u = *(const ushort4*)(baseB + (size_t)csrB[e] * ldpB);
            b0 += bf2f(u.x); b1 += bf2f(u.y); b2 += bf2f(u.z); b3 += bf2f(u.w);
        }
        float invB = 1.f / fmaxf((float)(endB - begB), 1.f);
        float4 bB = ((const float4*)sg.biasB)[lane];
        r0 += b0 * invB + bB.x;
        r1 += b1 * invB + bB.y;
        r2 += b2 * invB + bB.z;
        r3 += b3 * invB + bB.w;
    }

    size_t o = (size_t)node * sg.ldo + lane * 4;
    ushort4 cur = *(const ushort4*)(sg.outx + o);
    ushort4 w;
    w.x = f2bf(bf2f(cur.x) + r0);
    w.y = f2bf(bf2f(cur.y) + r1);
    w.z = f2bf(bf2f(cur.z) + r2);
    w.w = f2bf(bf2f(cur.w) + r3);
    *(ushort4*)(sg.outx + o) = w;
}

// ---------------- cosine: one wave per row ----------------
__global__ __launch_bounds__(256) void k_cos(const float* __restrict__ ro,
                                             const float* __restrict__ pr,
                                             const int* __restrict__ types,
                                             float* __restrict__ out, int nr) {
    int row = blockIdx.x * 4 + (threadIdx.x >> 6);
    int lane = threadIdx.x & 63;
    if (row >= nr) return;
    int t = types[row];
    float2 r = ((const float2*)(ro + (size_t)row * OUTD_))[lane];
    float2 nn = ((const float2*)(pr + (size_t)row * 384 + t * OUTD_))[lane];
    float num = r.x * nn.x + r.y * nn.y;
    float d1 = r.x * r.x + r.y * r.y;
    float d2 = nn.x * nn.x + nn.y * nn.y;
    #pragma unroll
    for (int s = 1; s < 64; s <<= 1) {
        num += __shfl_xor(num, s);
        d1 += __shfl_xor(d1, s);
        d2 += __shfl_xor(d2, s);
    }
    if (lane == 0) out[row] = (num / fmaxf(sqrtf(d1) * sqrtf(d2), 1e-8f) + 1.f) * 0.5f;
}

extern "C" void kernel_launch(void* const* d_in, const int* in_sizes, int n_in,
                              void* d_out, int out_size, void* d_ws, size_t ws_size,
                              hipStream_t stream) {
    const float* x_r0 = (const float*)d_in[0];
    const float* x_p0 = (const float*)d_in[1];
    const float* x_m0 = (const float*)d_in[2];
    const int* e_src[4] = {(const int*)d_in[3], (const int*)d_in[5], (const int*)d_in[7], (const int*)d_in[9]};
    const int* e_dst[4] = {(const int*)d_in[4], (const int*)d_in[6], (const int*)d_in[8], (const int*)d_in[10]};
    const float* notes = (const float*)d_in[11];
    const int* types = (const int*)d_in[12];
    const float* Wl0 = (const float*)d_in[13];
    const float* Wr0 = (const float*)d_in[14];
    const float* bl0 = (const float*)d_in[15];
    const float* WlL = (const float*)d_in[16];
    const float* WrL = (const float*)d_in[17];
    const float* blL = (const float*)d_in[18];
    const float* Wre = (const float*)d_in[19];
    const float* bre = (const float*)d_in[20];
    const float* Wn  = (const float*)d_in[21];
    const float* bn  = (const float*)d_in[22];
    float* out = (float*)d_out;

    // ---- workspace carve ----
    uintptr_t base = (uintptr_t)d_ws;
    auto alloc = [&](size_t bytes) -> void* {
        uintptr_t p = (base + 255) & ~(uintptr_t)255;
        base = p + bytes;
        return (void*)p;
    };
    unsigned short* Rb[2] = {(unsigned short*)alloc((size_t)NR_ * 768 * 2),
                             (unsigned short*)alloc((size_t)NR_ * 768 * 2)};
    unsigned short* Pb[2] = {(unsigned short*)alloc((size_t)NP2_ * 512 * 2),
                             (unsigned short*)alloc((size_t)NP2_ * 512 * 2)};
    unsigned short* Mb[2] = {(unsigned short*)alloc((size_t)NM_ * 512 * 2),
                             (unsigned short*)alloc((size_t)NM_ * 512 * 2)};
    float* ro = (float*)alloc((size_t)NR_ * OUTD_ * 4);
    float* pr = (float*)alloc((size_t)NR_ * 384 * 4);
    unsigned short* wbf = (unsigned short*)alloc((size_t)4000000 * 2);
    int* csum = (int*)alloc(160 * 4);
    int nd[4] = {NR_, NR_, NP2_, NM_};
    Csr4 cs{};
    for (int t = 0; t < 4; ++t) {
        cs.src[t] = e_src[t]; cs.dst[t] = e_dst[t]; cs.n[t] = nd[t];
        cs.offs[t] = (int*)alloc(((size_t)nd[t] + 1) * 4);
        cs.cur[t]  = (int*)alloc((size_t)nd[t] * 4);
        cs.csr[t]  = (int*)alloc((size_t)NE_ * 4);
    }

    // ---- weight transpose+convert: concatenated B blocks, bf16 [N][K] ----
    unsigned short *BR[4], *BP[4], *BM[4], *Bre, *Bn;
    {
        WBatch wb{};
        int cnt = 0;
        size_t woff = 0;
        auto add = [&](const float* a, const float* bb, int K, int N) -> unsigned short* {
            unsigned short* dst = wbf + woff;
            woff += (size_t)K * N;
            wb.it[cnt] = WItem{a, bb, dst, K, N};
            ++cnt;
            return dst;
        };
        const size_t w0 = (size_t)EMB_ * HID_;
        const size_t wl = (size_t)HID_ * HID_;
        for (int l = 0; l < 4; ++l) {
            int K = (l == 0) ? EMB_ : HID_;
            const float* Wr_ = (l == 0) ? Wr0 : WrL + (size_t)(l - 1) * 4 * wl;
            const float* Wl_ = (l == 0) ? Wl0 : WlL + (size_t)(l - 1) * 4 * wl;
            size_t ws_ = (l == 0) ? w0 : wl;
            BR[l] = add(Wr_ + 0 * ws_, Wr_ + 1 * ws_, K, HID_);  // WrC
            add(Wl_ + 2 * ws_, nullptr, K, HID_);                 // Wl2 (r2p proj)
            add(Wl_ + 3 * ws_, nullptr, K, HID_);                 // Wl3 (r2m proj)
            BP[l] = add(Wr_ + 2 * ws_, nullptr, K, HID_);         // Wr2
            add(Wl_ + 0 * ws_, nullptr, K, HID_);                 // Wl0 (p2r proj)
            BM[l] = add(Wr_ + 3 * ws_, nullptr, K, HID_);         // Wr3
            add(Wl_ + 1 * ws_, nullptr, K, HID_);                 // Wl1 (m2r proj)
        }
        Bre = add(Wre, nullptr, HID_, OUTD_);
        Bn = add(Wn + 0 * (size_t)EMB_ * OUTD_, nullptr, EMB_, OUTD_);
        add(Wn + 1 * (size_t)EMB_ * OUTD_, nullptr, EMB_, OUTD_);
        add(Wn + 2 * (size_t)EMB_ * OUTD_, nullptr, EMB_, OUTD_);
        k_wconvT<<<dim3(128, cnt), 256, 0, stream>>>(wb);
    }

    // ---- CSR build (batched over the 4 edge types) ----
    k_zero4<<<dim3((NP2_ + 255) / 256, 4), 256, 0, stream>>>(cs);
    k_deg4<<<dim3((NE_ + 255) / 256, 4), 256, 0, stream>>>(cs);
    k_scanA<<<dim3(40, 4), 256, 0, stream>>>(cs, csum);
    k_scanB<<<1, 64, 0, stream>>>(cs, csum);
    k_scanC<<<dim3((NP2_ + 255) / 256, 4), 256, 0, stream>>>(cs, csum);
    k_scatter4<<<dim3((NE_ + 255) / 256, 4), 256, 0, stream>>>(cs);

    // tile counts at BM=256
    const int MT_R = (NR_ + 255) / 256;    // 64
    const int MT_P = (NP2_ + 255) / 256;   // 157
    const int MT_M = (NM_ + 255) / 256;    // 118
    auto seg = [](const void* A, const unsigned short* Bt, void* C, const float* bias,
                  int lda, int ldc, int M, int K, int ntn, int blk0) -> GSeg {
        return GSeg{A, Bt, C, bias, lda, ldc, M, K, ntn, blk0};
    };

    const int AB_R = (NR_ + 3) / 4, AB_P = (NP2_ + 3) / 4, AB_M = (NM_ + 3) / 4;

    for (int l = 0; l < 4; ++l) {
        int K = (l == 0) ? EMB_ : HID_;
        unsigned short* R = Rb[l & 1];
        unsigned short* P = Pb[l & 1];
        unsigned short* M = Mb[l & 1];
        const float* bl_ = (l == 0) ? bl0 : blL + (size_t)(l - 1) * 4 * HID_;

        GBatch gb{};
        int nR = MT_R * 6, nP = MT_P * 4, nM = MT_M * 4;
        if (l == 0) {
            gb.s[0] = seg(x_r0, BR[0], R, nullptr, EMB_, 768, NR_, EMB_, 6, 0);
            gb.s[1] = seg(x_p0, BP[0], P, nullptr, EMB_, 512, NP2_, EMB_, 4, nR);
            gb.s[2] = seg(x_m0, BM[0], M, nullptr, EMB_, 512, NM_, EMB_, 4, nR + nP);
        } else {
            gb.s[0] = seg(Rb[(l - 1) & 1], BR[l], R, nullptr, 768, 768, NR_, K, 6, 0);
            gb.s[1] = seg(Pb[(l - 1) & 1], BP[l], P, nullptr, 512, 512, NP2_, K, 4, nR);
            gb.s[2] = seg(Mb[(l - 1) & 1], BM[l], M, nullptr, 512, 512, NM_, K, 4, nR + nP);
        }
        gb.b1 = nR; gb.b2 = nR + nP; gb.tot = nR + nP + nM;
        if (l == 0) k_gemmb<true, true><<<gb.tot, 512, 0, stream>>>(gb);
        else        k_gemmb<true, false><<<gb.tot, 512, 0, stream>>>(gb);

        // merged aggregates: reaction (p2r + m2r), protein (r2p), molecule (r2m)
        ABatch ab{};
        ab.s[0] = ASeg{cs.offs[0], cs.csr[0], P + 256, 512, bl_ + 0 * HID_,
                       cs.offs[1], cs.csr[1], M + 256, 512, bl_ + 1 * HID_,
                       R, 768, NR_, 0};
        ab.s[1] = ASeg{cs.offs[2], cs.csr[2], R + 256, 768, bl_ + 2 * HID_,
                       nullptr, nullptr, nullptr, 0, nullptr,
                       P, 512, NP2_, AB_R};
        ab.s[2] = ASeg{cs.offs[3], cs.csr[3], R + 512, 768, bl_ + 3 * HID_,
                       nullptr, nullptr, nullptr, 0, nullptr,
                       M, 512, NM_, AB_R + AB_P};
        ab.b1 = AB_R; ab.b2 = AB_R + AB_P;
        k_aggb<<<AB_R + AB_P + AB_M, 256, 0, stream>>>(ab);
    }

    // ---- finale: reaction proj (bf16-A) + notes projs (f32-A) + cosine ----
    {
        GBatch g1{};
        g1.s[0] = seg(Rb[1], Bre, ro, bre, 768, OUTD_, NR_, HID_, 1, 0);
        g1.b1 = g1.b2 = g1.tot = MT_R;
        k_gemmb<false, false><<<g1.tot, 512, 0, stream>>>(g1);
        GBatch g2{};
        g2.s[0] = seg(notes, Bn, pr, bn, EMB_, 384, NR_, EMB_, 3, 0);
        g2.b1 = g2.b2 = g2.tot = MT_R * 3;
        k_gemmb<false, true><<<g2.tot, 512, 0, stream>>>(g2);
    }
    k_cos<<<NR_ / 4, 256, 0, stream>>>(ro, pr, types, out, NR_);
}

// Round 14
// 764.707 us; speedup vs baseline: 2.8776x; 1.0946x over previous
//
#include <hip/hip_runtime.h>
#include <math.h>
#include <stdint.h>

#define NR_ 16384
#define NP2_ 40000
#define NM_ 30000
#define NE_ 200000
#define EMB_ 1024
#define HID_ 256
#define OUTD_ 128

typedef __attribute__((ext_vector_type(8))) short bf16x8;
typedef __attribute__((ext_vector_type(4))) float f32x4;
typedef __attribute__((ext_vector_type(8))) unsigned short us8;

__device__ __forceinline__ unsigned short f2bf(float f) {
    uint32_t u = __builtin_bit_cast(uint32_t, f);
    u = (u + 0x7FFFu + ((u >> 16) & 1u)) >> 16;
    return (unsigned short)u;
}
__device__ __forceinline__ float bf2f(unsigned short u) {
    uint32_t v = ((uint32_t)u) << 16;
    return __builtin_bit_cast(float, v);
}

// ---------------- batched CSR build ----------------
struct Csr4 {
    const int* src[4]; const int* dst[4];
    int* offs[4]; int* cur[4]; int* csr[4];
    int n[4];
};
__global__ void k_zero4(Csr4 c) {
    int y = blockIdx.y;
    int i = blockIdx.x * 256 + threadIdx.x;
    if (i < c.n[y]) c.cur[y][i] = 0;
}
__global__ void k_deg4(Csr4 c) {
    int y = blockIdx.y;
    int i = blockIdx.x * 256 + threadIdx.x;
    if (i < NE_) atomicAdd(&c.cur[y][c.dst[y][i]], 1);
}
__global__ void k_scanA(Csr4 c, int* __restrict__ csum) {
    int y = blockIdx.y;
    int n = c.n[y];
    int ch = blockIdx.x;
    int nch = (n + 1023) >> 10;
    if (ch >= nch) return;
    const int* deg = c.cur[y];
    int* offs = c.offs[y];
    __shared__ int ts[256];
    int base = ch << 10;
    int t = threadIdx.x;
    int v[4];
    int s = 0;
    #pragma unroll
    for (int k = 0; k < 4; ++k) {
        int i = base + t * 4 + k;
        v[k] = (i < n) ? deg[i] : 0;
        s += v[k];
    }
    ts[t] = s;
    __syncthreads();
    for (int st = 1; st < 256; st <<= 1) {
        int x = ts[t];
        int xo = (t >= st) ? ts[t - st] : 0;
        __syncthreads();
        ts[t] = x + xo;
        __syncthreads();
    }
    int run = (t > 0) ? ts[t - 1] : 0;
    #pragma unroll
    for (int k = 0; k < 4; ++k) {
        int i = base + t * 4 + k;
        if (i < n) offs[i] = run;
        run += v[k];
    }
    if (t == 255) csum[y * 40 + ch] = ts[255];
}
__global__ void k_scanB(Csr4 c, int* __restrict__ csum) {
    int y = threadIdx.x;
    if (y < 4) {
        int n = c.n[y];
        int nch = (n + 1023) >> 10;
        int acc = 0;
        for (int i = 0; i < nch; ++i) {
            int v = csum[y * 40 + i];
            csum[y * 40 + i] = acc;
            acc += v;
        }
        c.offs[y][n] = acc;
    }
}
__global__ void k_scanC(Csr4 c, const int* __restrict__ csum) {
    int y = blockIdx.y;
    int i = blockIdx.x * 256 + threadIdx.x;
    if (i < c.n[y]) {
        int v = c.offs[y][i] + csum[y * 40 + (i >> 10)];
        c.offs[y][i] = v;
        c.cur[y][i] = v;
    }
}
__global__ void k_scatter4(Csr4 c) {
    int y = blockIdx.y;
    int i = blockIdx.x * 256 + threadIdx.x;
    if (i < NE_) {
        int d = c.dst[y][i];
        int p = atomicAdd(&c.cur[y][d], 1);
        c.csr[y][p] = c.src[y][i];
    }
}

// batched weight transpose+convert: dst[n*K+k] = bf16(a[k*N+n] (+ b[k*N+n]))
struct WItem { const float* a; const float* b; unsigned short* dst; int k; int n; };
struct WBatch { WItem it[32]; };
__global__ void k_wconvT(WBatch wb) {
    WItem w = wb.it[blockIdx.y];
    int total = w.k * w.n;
    int kmask = w.k - 1;
    int shift = (w.k == 1024) ? 10 : 8;
    for (int idx = blockIdx.x * 256 + threadIdx.x; idx < total; idx += gridDim.x * 256) {
        int k = idx & kmask, n = idx >> shift;
        float v = w.a[(size_t)k * w.n + n];
        if (w.b) v += w.b[(size_t)k * w.n + n];
        w.dst[idx] = f2bf(v);
    }
}

struct GSeg {
    const void* A; const unsigned short* Bt; void* C; const float* bias;
    int lda, ldc, M, K, ntn, blk0;
};
struct GBatch { GSeg s[3]; int b1, b2, tot; };

// ---------------- bf16-A batched MFMA GEMM (round-8 proven core, bounds 256,3) ----------------
template <bool OBF>
__global__ __launch_bounds__(256, 3) void k_gemmb(GBatch gb) {
    __shared__ __align__(16) unsigned short As[128 * 64];
    __shared__ __align__(16) unsigned short Bs[128 * 64];
    const int tid = threadIdx.x;
    const int lane = tid & 63;
    int nwg = gb.tot;
    int o = blockIdx.x;
    int q = nwg >> 3, r = nwg & 7;
    int xcd = o & 7, j = o >> 3;
    int wg = (xcd < r ? xcd * (q + 1) : r * (q + 1) + (xcd - r) * q) + j;
    const int si = (wg >= gb.b1) + (wg >= gb.b2);
    const GSeg sg = gb.s[si];
    const int local = wg - sg.blk0;
    const int bm = (local / sg.ntn) * 128;
    const int bn = (local % sg.ntn) * 128;
    const int lda = sg.lda, ldc = sg.ldc, M = sg.M, K = sg.K;
    const unsigned short* __restrict__ Bt = sg.Bt;
    const float* __restrict__ bias = sg.bias;

    const int wave = tid >> 6;
    const int wr = (wave >> 1) * 64;
    const int wc = (wave & 1) * 64;
    const int frow = lane & 15;
    const int fkc = lane >> 4;
    f32x4 acc[4][4] = {};

    for (int k0 = 0; k0 < K; k0 += 64) {
        #pragma unroll
        for (int i = 0; i < 4; ++i) {
            int c = tid + i * 256;
            int row = c >> 3, kc = c & 7;
            int srck = k0 + ((kc ^ (row & 7)) << 3);
            int ga = min(bm + row, M - 1);
            __builtin_amdgcn_global_load_lds(
                (const __attribute__((address_space(1))) unsigned int*)((const unsigned short*)sg.A + (size_t)ga * lda + srck),
                (__attribute__((address_space(3))) unsigned int*)(As + (size_t)c * 8), 16, 0, 0);
            __builtin_amdgcn_global_load_lds(
                (const __attribute__((address_space(1))) unsigned int*)(Bt + (size_t)(bn + row) * K + srck),
                (__attribute__((address_space(3))) unsigned int*)(Bs + (size_t)c * 8), 16, 0, 0);
        }
        __syncthreads();
        #pragma unroll
        for (int kk = 0; kk < 2; ++kk) {
            bf16x8 af[4], bfr[4];
            #pragma unroll
            for (int m = 0; m < 4; ++m) {
                int row = wr + m * 16 + frow;
                int kc = kk * 4 + fkc;
                af[m] = *(const bf16x8*)(As + (size_t)((row << 3) + (kc ^ (row & 7))) * 8);
            }
            #pragma unroll
            for (int n = 0; n < 4; ++n) {
                int row = wc + n * 16 + frow;
                int kc = kk * 4 + fkc;
                bfr[n] = *(const bf16x8*)(Bs + (size_t)((row << 3) + (kc ^ (row & 7))) * 8);
            }
            #pragma unroll
            for (int m = 0; m < 4; ++m)
                #pragma unroll
                for (int n = 0; n < 4; ++n)
                    acc[m][n] = __builtin_amdgcn_mfma_f32_16x16x32_bf16(bfr[n], af[m], acc[m][n], 0, 0, 0);
        }
        __syncthreads();
    }

    const int ccol0 = (lane >> 4) << 2;
    #pragma unroll
    for (int m = 0; m < 4; ++m) {
        int row = bm + wr + m * 16 + frow;
        if (row < M) {
            #pragma unroll
            for (int n = 0; n < 4; ++n) {
                int col = bn + wc + n * 16 + ccol0;
                f32x4 v = acc[m][n];
                if (bias) {
                    v[0] += bias[col + 0];
                    v[1] += bias[col + 1];
                    v[2] += bias[col + 2];
                    v[3] += bias[col + 3];
                }
                if constexpr (OBF) {
                    ushort4 oo;
                    oo.x = f2bf(v[0]); oo.y = f2bf(v[1]); oo.z = f2bf(v[2]); oo.w = f2bf(v[3]);
                    *(ushort4*)((unsigned short*)sg.C + (size_t)row * ldc + col) = oo;
                } else {
                    *(float4*)((float*)sg.C + (size_t)row * ldc + col) = make_float4(v[0], v[1], v[2], v[3]);
                }
            }
        }
    }
}

// ---------------- f32-A pipelined MFMA GEMM (round-11 proven, bounds 256,3) ----------------
template <bool OBF>
__global__ __launch_bounds__(256, 3) void k_gemma(GBatch gb) {
    __shared__ __align__(16) unsigned short As[128 * 64];
    __shared__ __align__(16) unsigned short Bs[2][128 * 64];
    const int tid = threadIdx.x;
    const int lane = tid & 63;
    int nwg = gb.tot;
    int o = blockIdx.x;
    int q = nwg >> 3, r = nwg & 7;
    int xcd = o & 7, j = o >> 3;
    int wg = (xcd < r ? xcd * (q + 1) : r * (q + 1) + (xcd - r) * q) + j;
    const int si = (wg >= gb.b1) + (wg >= gb.b2);
    const GSeg sg = gb.s[si];
    const int local = wg - sg.blk0;
    const int bm = (local / sg.ntn) * 128;
    const int bn = (local % sg.ntn) * 128;
    const int lda = sg.lda, ldc = sg.ldc, M = sg.M, K = sg.K;
    const unsigned short* __restrict__ Bt = sg.Bt;
    const float* __restrict__ bias = sg.bias;

    const int wave = tid >> 6;
    const int wr = (wave >> 1) * 64;
    const int wc = (wave & 1) * 64;
    const int frow = lane & 15;
    const int fkc = lane >> 4;
    f32x4 acc[4][4] = {};
    float4 ra0[4], ra1[4];

#define ALOAD(kk0) do {                                                                    \
    _Pragma("unroll")                                                                      \
    for (int i = 0; i < 4; ++i) {                                                          \
        int c = tid + i * 256, rw = c >> 3, kc = c & 7;                                    \
        int srck = (kk0) + ((kc ^ (rw & 7)) << 3);                                         \
        int ga = min(bm + rw, M - 1);                                                      \
        const float* Af = (const float*)sg.A + (size_t)ga * lda + srck;                    \
        ra0[i] = *(const float4*)Af;                                                       \
        ra1[i] = *(const float4*)(Af + 4);                                                 \
    } } while (0)

#define AWRITE() do {                                                                      \
    _Pragma("unroll")                                                                      \
    for (int i = 0; i < 4; ++i) {                                                          \
        int c = tid + i * 256;                                                             \
        us8 oo;                                                                            \
        oo[0] = f2bf(ra0[i].x); oo[1] = f2bf(ra0[i].y);                                    \
        oo[2] = f2bf(ra0[i].z); oo[3] = f2bf(ra0[i].w);                                    \
        oo[4] = f2bf(ra1[i].x); oo[5] = f2bf(ra1[i].y);                                    \
        oo[6] = f2bf(ra1[i].z); oo[7] = f2bf(ra1[i].w);                                    \
        *(us8*)(As + (size_t)c * 8) = oo;                                                  \
    } } while (0)

#define STAGE_B(bufi, kk0) do {                                                            \
    _Pragma("unroll")                                                                      \
    for (int i = 0; i < 4; ++i) {                                                          \
        int c = tid + i * 256, rw = c >> 3, kc = c & 7;                                    \
        int srck = (kk0) + ((kc ^ (rw & 7)) << 3);                                         \
        __builtin_amdgcn_global_load_lds(                                                  \
            (const __attribute__((address_space(1))) unsigned int*)(Bt + (size_t)(bn + rw) * K + srck), \
            (__attribute__((address_space(3))) unsigned int*)(&Bs[bufi][(size_t)c * 8]), 16, 0, 0); \
    } } while (0)

#define COMPUTE(bufi) do {                                                                 \
    _Pragma("unroll")                                                                      \
    for (int kk = 0; kk < 2; ++kk) {                                                       \
        bf16x8 af[4], bfr[4];                                                              \
        _Pragma("unroll")                                                                  \
        for (int m = 0; m < 4; ++m) {                                                      \
            int rw = wr + m * 16 + frow;                                                   \
            int kc = kk * 4 + fkc;                                                         \
            af[m] = *(const bf16x8*)(As + (size_t)((rw << 3) + (kc ^ (rw & 7))) * 8);      \
        }                                                                                  \
        _Pragma("unroll")                                                                  \
        for (int n = 0; n < 4; ++n) {                                                      \
            int rw = wc + n * 16 + frow;                                                   \
            int kc = kk * 4 + fkc;                                                         \
            bfr[n] = *(const bf16x8*)(&Bs[bufi][(size_t)((rw << 3) + (kc ^ (rw & 7))) * 8]); \
        }                                                                                  \
        _Pragma("unroll")                                                                  \
        for (int m = 0; m < 4; ++m)                                                        \
            _Pragma("unroll")                                                              \
            for (int n = 0; n < 4; ++n)                                                    \
                acc[m][n] = __builtin_amdgcn_mfma_f32_16x16x32_bf16(bfr[n], af[m], acc[m][n], 0, 0, 0); \
    } } while (0)

    const int nt = K >> 6;
    ALOAD(0);
    STAGE_B(0, 0);
    AWRITE();
    __syncthreads();
    for (int t = 0; t < nt; ++t) {
        if (t + 1 < nt) {
            ALOAD((t + 1) << 6);
            STAGE_B((t + 1) & 1, (t + 1) << 6);
        }
        COMPUTE(t & 1);
        __syncthreads();
        if (t + 1 < nt) AWRITE();
        __syncthreads();
    }
#undef ALOAD
#undef AWRITE
#undef STAGE_B
#undef COMPUTE

    const int ccol0 = (lane >> 4) << 2;
    #pragma unroll
    for (int m = 0; m < 4; ++m) {
        int row = bm + wr + m * 16 + frow;
        if (row < M) {
            #pragma unroll
            for (int n = 0; n < 4; ++n) {
                int col = bn + wc + n * 16 + ccol0;
                f32x4 v = acc[m][n];
                if (bias) {
                    v[0] += bias[col + 0];
                    v[1] += bias[col + 1];
                    v[2] += bias[col + 2];
                    v[3] += bias[col + 3];
                }
                if constexpr (OBF) {
                    ushort4 oo;
                    oo.x = f2bf(v[0]); oo.y = f2bf(v[1]); oo.z = f2bf(v[2]); oo.w = f2bf(v[3]);
                    *(ushort4*)((unsigned short*)sg.C + (size_t)row * ldc + col) = oo;
                } else {
                    *(float4*)((float*)sg.C + (size_t)row * ldc + col) = make_float4(v[0], v[1], v[2], v[3]);
                }
            }
        }
    }
}

// ---------------- merged CSR mean-aggregate, lane-parallel index prefetch ----------------
// One wave per node. Indices for up to 64 edges fetched in ONE vector load
// (csr[beg+lane]) then __shfl-broadcast -> all row gathers in the unrolled body are
// independent (no uniform-load on the critical path). Summation order unchanged.
struct ASeg {
    const int* offsA; const int* csrA; const unsigned short* projA; int ldpA; const float* biasA;
    const int* offsB; const int* csrB; const unsigned short* projB; int ldpB; const float* biasB;
    unsigned short* outx; int ldo; int ndst; int blk0;
};
struct ABatch { ASeg s[3]; int b1, b2; };

__device__ __forceinline__ void agg_sum(const int* __restrict__ csr, int beg, int end,
                                        const unsigned short* __restrict__ base, int ldp,
                                        int lane, float& s0, float& s1, float& s2, float& s3) {
    for (int b = beg; b < end; b += 64) {
        int cnt = min(64, end - b);
        int myidx = csr[min(b + lane, end - 1)];
        int g = 0;
        for (; g + 3 < cnt; g += 4) {
            int i0 = __shfl(myidx, g);
            int i1 = __shfl(myidx, g + 1);
            int i2 = __shfl(myidx, g + 2);
            int i3 = __shfl(myidx, g + 3);
            ushort4 u0 = *(const ushort4*)(base + (size_t)i0 * ldp);
            ushort4 u1 = *(const ushort4*)(base + (size_t)i1 * ldp);
            ushort4 u2 = *(const ushort4*)(base + (size_t)i2 * ldp);
            ushort4 u3 = *(const ushort4*)(base + (size_t)i3 * ldp);
            s0 += bf2f(u0.x) + bf2f(u1.x) + bf2f(u2.x) + bf2f(u3.x);
            s1 += bf2f(u0.y) + bf2f(u1.y) + bf2f(u2.y) + bf2f(u3.y);
            s2 += bf2f(u0.z) + bf2f(u1.z) + bf2f(u2.z) + bf2f(u3.z);
            s3 += bf2f(u0.w) + bf2f(u1.w) + bf2f(u2.w) + bf2f(u3.w);
        }
        for (; g < cnt; ++g) {
            int i = __shfl(myidx, g);
            ushort4 u = *(const ushort4*)(base + (size_t)i * ldp);
            s0 += bf2f(u.x); s1 += bf2f(u.y); s2 += bf2f(u.z); s3 += bf2f(u.w);
        }
    }
}

__global__ __launch_bounds__(256) void k_aggb(ABatch ab) {
    int b = blockIdx.x;
    int si = (b >= ab.b1) + (b >= ab.b2);
    const ASeg sg = ab.s[si];
    int node = (b - sg.blk0) * 4 + (threadIdx.x >> 6);
    int lane = threadIdx.x & 63;
    if (node >= sg.ndst) return;

    float a0 = 0.f, a1 = 0.f, a2 = 0.f, a3 = 0.f;
    int begA = sg.offsA[node], endA = sg.offsA[node + 1];
    agg_sum(sg.csrA, begA, endA, sg.projA + lane * 4, sg.ldpA, lane, a0, a1, a2, a3);
    float invA = 1.f / fmaxf((float)(endA - begA), 1.f);
    float4 bA = ((const float4*)sg.biasA)[lane];
    float r0 = a0 * invA + bA.x;
    float r1 = a1 * invA + bA.y;
    float r2 = a2 * invA + bA.z;
    float r3 = a3 * invA + bA.w;

    if (sg.csrB) {
        float b0 = 0.f, b1 = 0.f, b2 = 0.f, b3 = 0.f;
        int begB = sg.offsB[node], endB = sg.offsB[node + 1];
        agg_sum(sg.csrB, begB, endB, sg.projB + lane * 4, sg.ldpB, lane, b0, b1, b2, b3);
        float invB = 1.f / fmaxf((float)(endB - begB), 1.f);
        float4 bB = ((const float4*)sg.biasB)[lane];
        r0 += b0 * invB + bB.x;
        r1 += b1 * invB + bB.y;
        r2 += b2 * invB + bB.z;
        r3 += b3 * invB + bB.w;
    }

    size_t o = (size_t)node * sg.ldo + lane * 4;
    ushort4 cur = *(const ushort4*)(sg.outx + o);
    ushort4 w;
    w.x = f2bf(bf2f(cur.x) + r0);
    w.y = f2bf(bf2f(cur.y) + r1);
    w.z = f2bf(bf2f(cur.z) + r2);
    w.w = f2bf(bf2f(cur.w) + r3);
    *(ushort4*)(sg.outx + o) = w;
}

// ---------------- cosine: one wave per row ----------------
__global__ __launch_bounds__(256) void k_cos(const float* __restrict__ ro,
                                             const float* __restrict__ pr,
                                             const int* __restrict__ types,
                                             float* __restrict__ out, int nr) {
    int row = blockIdx.x * 4 + (threadIdx.x >> 6);
    int lane = threadIdx.x & 63;
    if (row >= nr) return;
    int t = types[row];
    float2 r = ((const float2*)(ro + (size_t)row * OUTD_))[lane];
    float2 nn = ((const float2*)(pr + (size_t)row * 384 + t * OUTD_))[lane];
    float num = r.x * nn.x + r.y * nn.y;
    float d1 = r.x * r.x + r.y * r.y;
    float d2 = nn.x * nn.x + nn.y * nn.y;
    #pragma unroll
    for (int s = 1; s < 64; s <<= 1) {
        num += __shfl_xor(num, s);
        d1 += __shfl_xor(d1, s);
        d2 += __shfl_xor(d2, s);
    }
    if (lane == 0) out[row] = (num / fmaxf(sqrtf(d1) * sqrtf(d2), 1e-8f) + 1.f) * 0.5f;
}

extern "C" void kernel_launch(void* const* d_in, const int* in_sizes, int n_in,
                              void* d_out, int out_size, void* d_ws, size_t ws_size,
                              hipStream_t stream) {
    const float* x_r0 = (const float*)d_in[0];
    const float* x_p0 = (const float*)d_in[1];
    const float* x_m0 = (const float*)d_in[2];
    const int* e_src[4] = {(const int*)d_in[3], (const int*)d_in[5], (const int*)d_in[7], (const int*)d_in[9]};
    const int* e_dst[4] = {(const int*)d_in[4], (const int*)d_in[6], (const int*)d_in[8], (const int*)d_in[10]};
    const float* notes = (const float*)d_in[11];
    const int* types = (const int*)d_in[12];
    const float* Wl0 = (const float*)d_in[13];
    const float* Wr0 = (const float*)d_in[14];
    const float* bl0 = (const float*)d_in[15];
    const float* WlL = (const float*)d_in[16];
    const float* WrL = (const float*)d_in[17];
    const float* blL = (const float*)d_in[18];
    const float* Wre = (const float*)d_in[19];
    const float* bre = (const float*)d_in[20];
    const float* Wn  = (const float*)d_in[21];
    const float* bn  = (const float*)d_in[22];
    float* out = (float*)d_out;

    // ---- workspace carve ----
    uintptr_t base = (uintptr_t)d_ws;
    auto alloc = [&](size_t bytes) -> void* {
        uintptr_t p = (base + 255) & ~(uintptr_t)255;
        base = p + bytes;
        return (void*)p;
    };
    unsigned short* Rb[2] = {(unsigned short*)alloc((size_t)NR_ * 768 * 2),
                             (unsigned short*)alloc((size_t)NR_ * 768 * 2)};
    unsigned short* Pb[2] = {(unsigned short*)alloc((size_t)NP2_ * 512 * 2),
                             (unsigned short*)alloc((size_t)NP2_ * 512 * 2)};
    unsigned short* Mb[2] = {(unsigned short*)alloc((size_t)NM_ * 512 * 2),
                             (unsigned short*)alloc((size_t)NM_ * 512 * 2)};
    float* ro = (float*)alloc((size_t)NR_ * OUTD_ * 4);
    float* pr = (float*)alloc((size_t)NR_ * 384 * 4);
    unsigned short* wbf = (unsigned short*)alloc((size_t)4000000 * 2);
    int* csum = (int*)alloc(160 * 4);
    int nd[4] = {NR_, NR_, NP2_, NM_};
    Csr4 cs{};
    for (int t = 0; t < 4; ++t) {
        cs.src[t] = e_src[t]; cs.dst[t] = e_dst[t]; cs.n[t] = nd[t];
        cs.offs[t] = (int*)alloc(((size_t)nd[t] + 1) * 4);
        cs.cur[t]  = (int*)alloc((size_t)nd[t] * 4);
        cs.csr[t]  = (int*)alloc((size_t)NE_ * 4);
    }

    // ---- weight transpose+convert: concatenated B blocks, bf16 [N][K] ----
    unsigned short *BR[4], *BP[4], *BM[4], *Bre, *Bn;
    {
        WBatch wb{};
        int cnt = 0;
        size_t woff = 0;
        auto add = [&](const float* a, const float* bb, int K, int N) -> unsigned short* {
            unsigned short* dst = wbf + woff;
            woff += (size_t)K * N;
            wb.it[cnt] = WItem{a, bb, dst, K, N};
            ++cnt;
            return dst;
        };
        const size_t w0 = (size_t)EMB_ * HID_;
        const size_t wl = (size_t)HID_ * HID_;
        for (int l = 0; l < 4; ++l) {
            int K = (l == 0) ? EMB_ : HID_;
            const float* Wr_ = (l == 0) ? Wr0 : WrL + (size_t)(l - 1) * 4 * wl;
            const float* Wl_ = (l == 0) ? Wl0 : WlL + (size_t)(l - 1) * 4 * wl;
            size_t ws_ = (l == 0) ? w0 : wl;
            BR[l] = add(Wr_ + 0 * ws_, Wr_ + 1 * ws_, K, HID_);  // WrC
            add(Wl_ + 2 * ws_, nullptr, K, HID_);                 // Wl2 (r2p proj)
            add(Wl_ + 3 * ws_, nullptr, K, HID_);                 // Wl3 (r2m proj)
            BP[l] = add(Wr_ + 2 * ws_, nullptr, K, HID_);         // Wr2
            add(Wl_ + 0 * ws_, nullptr, K, HID_);                 // Wl0 (p2r proj)
            BM[l] = add(Wr_ + 3 * ws_, nullptr, K, HID_);         // Wr3
            add(Wl_ + 1 * ws_, nullptr, K, HID_);                 // Wl1 (m2r proj)
        }
        Bre = add(Wre, nullptr, HID_, OUTD_);
        Bn = add(Wn + 0 * (size_t)EMB_ * OUTD_, nullptr, EMB_, OUTD_);
        add(Wn + 1 * (size_t)EMB_ * OUTD_, nullptr, EMB_, OUTD_);
        add(Wn + 2 * (size_t)EMB_ * OUTD_, nullptr, EMB_, OUTD_);
        k_wconvT<<<dim3(128, cnt), 256, 0, stream>>>(wb);
    }

    // ---- CSR build (batched over the 4 edge types) ----
    k_zero4<<<dim3((NP2_ + 255) / 256, 4), 256, 0, stream>>>(cs);
    k_deg4<<<dim3((NE_ + 255) / 256, 4), 256, 0, stream>>>(cs);
    k_scanA<<<dim3(40, 4), 256, 0, stream>>>(cs, csum);
    k_scanB<<<1, 64, 0, stream>>>(cs, csum);
    k_scanC<<<dim3((NP2_ + 255) / 256, 4), 256, 0, stream>>>(cs, csum);
    k_scatter4<<<dim3((NE_ + 255) / 256, 4), 256, 0, stream>>>(cs);

    const int MT_R = (NR_ + 127) / 128;    // 128
    const int MT_P = (NP2_ + 127) / 128;   // 313
    const int MT_M = (NM_ + 127) / 128;    // 235
    auto seg = [](const void* A, const unsigned short* Bt, void* C, const float* bias,
                  int lda, int ldc, int M, int K, int ntn, int blk0) -> GSeg {
        return GSeg{A, Bt, C, bias, lda, ldc, M, K, ntn, blk0};
    };

    const int AB_R = (NR_ + 3) / 4, AB_P = (NP2_ + 3) / 4, AB_M = (NM_ + 3) / 4;

    for (int l = 0; l < 4; ++l) {
        int K = (l == 0) ? EMB_ : HID_;
        unsigned short* R = Rb[l & 1];
        unsigned short* P = Pb[l & 1];
        unsigned short* M = Mb[l & 1];
        const float* bl_ = (l == 0) ? bl0 : blL + (size_t)(l - 1) * 4 * HID_;

        GBatch gb{};
        int nR = MT_R * 6, nP = MT_P * 4, nM = MT_M * 4;
        if (l == 0) {
            gb.s[0] = seg(x_r0, BR[0], R, nullptr, EMB_, 768, NR_, EMB_, 6, 0);
            gb.s[1] = seg(x_p0, BP[0], P, nullptr, EMB_, 512, NP2_, EMB_, 4, nR);
            gb.s[2] = seg(x_m0, BM[0], M, nullptr, EMB_, 512, NM_, EMB_, 4, nR + nP);
        } else {
            gb.s[0] = seg(Rb[(l - 1) & 1], BR[l], R, nullptr, 768, 768, NR_, K, 6, 0);
            gb.s[1] = seg(Pb[(l - 1) & 1], BP[l], P, nullptr, 512, 512, NP2_, K, 4, nR);
            gb.s[2] = seg(Mb[(l - 1) & 1], BM[l], M, nullptr, 512, 512, NM_, K, 4, nR + nP);
        }
        gb.b1 = nR; gb.b2 = nR + nP; gb.tot = nR + nP + nM;
        if (l == 0) k_gemma<true><<<gb.tot, 256, 0, stream>>>(gb);
        else        k_gemmb<true><<<gb.tot, 256, 0, stream>>>(gb);

        // merged aggregates: reaction (p2r + m2r), protein (r2p), molecule (r2m)
        ABatch ab{};
        ab.s[0] = ASeg{cs.offs[0], cs.csr[0], P + 256, 512, bl_ + 0 * HID_,
                       cs.offs[1], cs.csr[1], M + 256, 512, bl_ + 1 * HID_,
                       R, 768, NR_, 0};
        ab.s[1] = ASeg{cs.offs[2], cs.csr[2], R + 256, 768, bl_ + 2 * HID_,
                       nullptr, nullptr, nullptr, 0, nullptr,
                       P, 512, NP2_, AB_R};
        ab.s[2] = ASeg{cs.offs[3], cs.csr[3], R + 512, 768, bl_ + 3 * HID_,
                       nullptr, nullptr, nullptr, 0, nullptr,
                       M, 512, NM_, AB_R + AB_P};
        ab.b1 = AB_R; ab.b2 = AB_R + AB_P;
        k_aggb<<<AB_R + AB_P + AB_M, 256, 0, stream>>>(ab);
    }

    // ---- finale: reaction proj (bf16-A) + notes projs (f32-A pipelined) + cosine ----
    {
        GBatch g1{};
        g1.s[0] = seg(Rb[1], Bre, ro, bre, 768, OUTD_, NR_, HID_, 1, 0);
        g1.b1 = g1.b2 = g1.tot = MT_R;
        k_gemmb<false><<<g1.tot, 256, 0, stream>>>(g1);
        GBatch g2{};
        g2.s[0] = seg(notes, Bn, pr, bn, EMB_, 384, NR_, EMB_, 3, 0);
        g2.b1 = g2.b2 = g2.tot = MT_R * 3;
        k_gemma<false><<<g2.tot, 256, 0, stream>>>(g2);
    }
    k_cos<<<NR_ / 4, 256, 0, stream>>>(ro, pr, types, out, NR_);
}

// Round 15
// 747.352 us; speedup vs baseline: 2.9445x; 1.0232x over previous
//
#include <hip/hip_runtime.h>
#include <hip/hip_bf16.h>
#include <math.h>
#include <stdint.h>

#define NR_ 16384
#define NP2_ 40000
#define NM_ 30000
#define NE_ 200000
#define EMB_ 1024
#define HID_ 256
#define OUTD_ 128

typedef __attribute__((ext_vector_type(8))) short bf16x8;
typedef __attribute__((ext_vector_type(4))) float f32x4;
typedef __attribute__((ext_vector_type(8))) unsigned short us8;

// hardware-path f32->bf16 (RNE): plain cast lets the compiler emit v_cvt_pk_bf16_f32
__device__ __forceinline__ unsigned short f2bf(float f) {
    return __builtin_bit_cast(unsigned short, __float2bfloat16(f));
}
__device__ __forceinline__ float bf2f(unsigned short u) {
    uint32_t v = ((uint32_t)u) << 16;
    return __builtin_bit_cast(float, v);
}

// ---------------- batched CSR build ----------------
struct Csr4 {
    const int* src[4]; const int* dst[4];
    int* offs[4]; int* cur[4]; int* csr[4];
    int n[4];
};
__global__ void k_zero4(Csr4 c) {
    int y = blockIdx.y;
    int i = blockIdx.x * 256 + threadIdx.x;
    if (i < c.n[y]) c.cur[y][i] = 0;
}
__global__ void k_deg4(Csr4 c) {
    int y = blockIdx.y;
    int i = blockIdx.x * 256 + threadIdx.x;
    if (i < NE_) atomicAdd(&c.cur[y][c.dst[y][i]], 1);
}
__global__ void k_scanA(Csr4 c, int* __restrict__ csum) {
    int y = blockIdx.y;
    int n = c.n[y];
    int ch = blockIdx.x;
    int nch = (n + 1023) >> 10;
    if (ch >= nch) return;
    const int* deg = c.cur[y];
    int* offs = c.offs[y];
    __shared__ int ts[256];
    int base = ch << 10;
    int t = threadIdx.x;
    int v[4];
    int s = 0;
    #pragma unroll
    for (int k = 0; k < 4; ++k) {
        int i = base + t * 4 + k;
        v[k] = (i < n) ? deg[i] : 0;
        s += v[k];
    }
    ts[t] = s;
    __syncthreads();
    for (int st = 1; st < 256; st <<= 1) {
        int x = ts[t];
        int xo = (t >= st) ? ts[t - st] : 0;
        __syncthreads();
        ts[t] = x + xo;
        __syncthreads();
    }
    int run = (t > 0) ? ts[t - 1] : 0;
    #pragma unroll
    for (int k = 0; k < 4; ++k) {
        int i = base + t * 4 + k;
        if (i < n) offs[i] = run;
        run += v[k];
    }
    if (t == 255) csum[y * 40 + ch] = ts[255];
}
__global__ void k_scanB(Csr4 c, int* __restrict__ csum) {
    int y = threadIdx.x;
    if (y < 4) {
        int n = c.n[y];
        int nch = (n + 1023) >> 10;
        int acc = 0;
        for (int i = 0; i < nch; ++i) {
            int v = csum[y * 40 + i];
            csum[y * 40 + i] = acc;
            acc += v;
        }
        c.offs[y][n] = acc;
    }
}
__global__ void k_scanC(Csr4 c, const int* __restrict__ csum) {
    int y = blockIdx.y;
    int i = blockIdx.x * 256 + threadIdx.x;
    if (i < c.n[y]) {
        int v = c.offs[y][i] + csum[y * 40 + (i >> 10)];
        c.offs[y][i] = v;
        c.cur[y][i] = v;
    }
}
__global__ void k_scatter4(Csr4 c) {
    int y = blockIdx.y;
    int i = blockIdx.x * 256 + threadIdx.x;
    if (i < NE_) {
        int d = c.dst[y][i];
        int p = atomicAdd(&c.cur[y][d], 1);
        c.csr[y][p] = c.src[y][i];
    }
}

// batched weight transpose+convert: dst[n*K+k] = bf16(a[k*N+n] (+ b[k*N+n]))
struct WItem { const float* a; const float* b; unsigned short* dst; int k; int n; };
struct WBatch { WItem it[32]; };
__global__ void k_wconvT(WBatch wb) {
    WItem w = wb.it[blockIdx.y];
    int total = w.k * w.n;
    int kmask = w.k - 1;
    int shift = (w.k == 1024) ? 10 : 8;
    for (int idx = blockIdx.x * 256 + threadIdx.x; idx < total; idx += gridDim.x * 256) {
        int k = idx & kmask, n = idx >> shift;
        float v = w.a[(size_t)k * w.n + n];
        if (w.b) v += w.b[(size_t)k * w.n + n];
        w.dst[idx] = f2bf(v);
    }
}

struct GSeg {
    const void* A; const unsigned short* Bt; void* C; const float* bias;
    int lda, ldc, M, K, ntn, blk0;
};
struct GBatch { GSeg s[3]; int b1, b2, tot; };

// ---------------- bf16-A batched MFMA GEMM (round-8 proven core, bounds 256,3) ----------------
template <bool OBF>
__global__ __launch_bounds__(256, 3) void k_gemmb(GBatch gb) {
    __shared__ __align__(16) unsigned short As[128 * 64];
    __shared__ __align__(16) unsigned short Bs[128 * 64];
    const int tid = threadIdx.x;
    const int lane = tid & 63;
    int nwg = gb.tot;
    int o = blockIdx.x;
    int q = nwg >> 3, r = nwg & 7;
    int xcd = o & 7, j = o >> 3;
    int wg = (xcd < r ? xcd * (q + 1) : r * (q + 1) + (xcd - r) * q) + j;
    const int si = (wg >= gb.b1) + (wg >= gb.b2);
    const GSeg sg = gb.s[si];
    const int local = wg - sg.blk0;
    const int bm = (local / sg.ntn) * 128;
    const int bn = (local % sg.ntn) * 128;
    const int lda = sg.lda, ldc = sg.ldc, M = sg.M, K = sg.K;
    const unsigned short* __restrict__ Bt = sg.Bt;
    const float* __restrict__ bias = sg.bias;

    const int wave = tid >> 6;
    const int wr = (wave >> 1) * 64;
    const int wc = (wave & 1) * 64;
    const int frow = lane & 15;
    const int fkc = lane >> 4;
    f32x4 acc[4][4] = {};

    for (int k0 = 0; k0 < K; k0 += 64) {
        #pragma unroll
        for (int i = 0; i < 4; ++i) {
            int c = tid + i * 256;
            int row = c >> 3, kc = c & 7;
            int srck = k0 + ((kc ^ (row & 7)) << 3);
            int ga = min(bm + row, M - 1);
            __builtin_amdgcn_global_load_lds(
                (const __attribute__((address_space(1))) unsigned int*)((const unsigned short*)sg.A + (size_t)ga * lda + srck),
                (__attribute__((address_space(3))) unsigned int*)(As + (size_t)c * 8), 16, 0, 0);
            __builtin_amdgcn_global_load_lds(
                (const __attribute__((address_space(1))) unsigned int*)(Bt + (size_t)(bn + row) * K + srck),
                (__attribute__((address_space(3))) unsigned int*)(Bs + (size_t)c * 8), 16, 0, 0);
        }
        __syncthreads();
        #pragma unroll
        for (int kk = 0; kk < 2; ++kk) {
            bf16x8 af[4], bfr[4];
            #pragma unroll
            for (int m = 0; m < 4; ++m) {
                int row = wr + m * 16 + frow;
                int kc = kk * 4 + fkc;
                af[m] = *(const bf16x8*)(As + (size_t)((row << 3) + (kc ^ (row & 7))) * 8);
            }
            #pragma unroll
            for (int n = 0; n < 4; ++n) {
                int row = wc + n * 16 + frow;
                int kc = kk * 4 + fkc;
                bfr[n] = *(const bf16x8*)(Bs + (size_t)((row << 3) + (kc ^ (row & 7))) * 8);
            }
            #pragma unroll
            for (int m = 0; m < 4; ++m)
                #pragma unroll
                for (int n = 0; n < 4; ++n)
                    acc[m][n] = __builtin_amdgcn_mfma_f32_16x16x32_bf16(bfr[n], af[m], acc[m][n], 0, 0, 0);
        }
        __syncthreads();
    }

    const int ccol0 = (lane >> 4) << 2;
    #pragma unroll
    for (int m = 0; m < 4; ++m) {
        int row = bm + wr + m * 16 + frow;
        if (row < M) {
            #pragma unroll
            for (int n = 0; n < 4; ++n) {
                int col = bn + wc + n * 16 + ccol0;
                f32x4 v = acc[m][n];
                if (bias) {
                    v[0] += bias[col + 0];
                    v[1] += bias[col + 1];
                    v[2] += bias[col + 2];
                    v[3] += bias[col + 3];
                }
                if constexpr (OBF) {
                    ushort4 oo;
                    oo.x = f2bf(v[0]); oo.y = f2bf(v[1]); oo.z = f2bf(v[2]); oo.w = f2bf(v[3]);
                    *(ushort4*)((unsigned short*)sg.C + (size_t)row * ldc + col) = oo;
                } else {
                    *(float4*)((float*)sg.C + (size_t)row * ldc + col) = make_float4(v[0], v[1], v[2], v[3]);
                }
            }
        }
    }
}

// ---------------- f32-A pipelined MFMA GEMM (round-11 proven, bounds 256,3) ----------------
template <bool OBF>
__global__ __launch_bounds__(256, 3) void k_gemma(GBatch gb) {
    __shared__ __align__(16) unsigned short As[128 * 64];
    __shared__ __align__(16) unsigned short Bs[2][128 * 64];
    const int tid = threadIdx.x;
    const int lane = tid & 63;
    int nwg = gb.tot;
    int o = blockIdx.x;
    int q = nwg >> 3, r = nwg & 7;
    int xcd = o & 7, j = o >> 3;
    int wg = (xcd < r ? xcd * (q + 1) : r * (q + 1) + (xcd - r) * q) + j;
    const int si = (wg >= gb.b1) + (wg >= gb.b2);
    const GSeg sg = gb.s[si];
    const int local = wg - sg.blk0;
    const int bm = (local / sg.ntn) * 128;
    const int bn = (local % sg.ntn) * 128;
    const int lda = sg.lda, ldc = sg.ldc, M = sg.M, K = sg.K;
    const unsigned short* __restrict__ Bt = sg.Bt;
    const float* __restrict__ bias = sg.bias;

    const int wave = tid >> 6;
    const int wr = (wave >> 1) * 64;
    const int wc = (wave & 1) * 64;
    const int frow = lane & 15;
    const int fkc = lane >> 4;
    f32x4 acc[4][4] = {};
    float4 ra0[4], ra1[4];

#define ALOAD(kk0) do {                                                                    \
    _Pragma("unroll")                                                                      \
    for (int i = 0; i < 4; ++i) {                                                          \
        int c = tid + i * 256, rw = c >> 3, kc = c & 7;                                    \
        int srck = (kk0) + ((kc ^ (rw & 7)) << 3);                                         \
        int ga = min(bm + rw, M - 1);                                                      \
        const float* Af = (const float*)sg.A + (size_t)ga * lda + srck;                    \
        ra0[i] = *(const float4*)Af;                                                       \
        ra1[i] = *(const float4*)(Af + 4);                                                 \
    } } while (0)

#define AWRITE() do {                                                                      \
    _Pragma("unroll")                                                                      \
    for (int i = 0; i < 4; ++i) {                                                          \
        int c = tid + i * 256;                                                             \
        us8 oo;                                                                            \
        oo[0] = f2bf(ra0[i].x); oo[1] = f2bf(ra0[i].y);                                    \
        oo[2] = f2bf(ra0[i].z); oo[3] = f2bf(ra0[i].w);                                    \
        oo[4] = f2bf(ra1[i].x); oo[5] = f2bf(ra1[i].y);                                    \
        oo[6] = f2bf(ra1[i].z); oo[7] = f2bf(ra1[i].w);                                    \
        *(us8*)(As + (size_t)c * 8) = oo;                                                  \
    } } while (0)

#define STAGE_B(bufi, kk0) do {                                                            \
    _Pragma("unroll")                                                                      \
    for (int i = 0; i < 4; ++i) {                                                          \
        int c = tid + i * 256, rw = c >> 3, kc = c & 7;                                    \
        int srck = (kk0) + ((kc ^ (rw & 7)) << 3);                                         \
        __builtin_amdgcn_global_load_lds(                                                  \
            (const __attribute__((address_space(1))) unsigned int*)(Bt + (size_t)(bn + rw) * K + srck), \
            (__attribute__((address_space(3))) unsigned int*)(&Bs[bufi][(size_t)c * 8]), 16, 0, 0); \
    } } while (0)

#define COMPUTE(bufi) do {                                                                 \
    _Pragma("unroll")                                                                      \
    for (int kk = 0; kk < 2; ++kk) {                                                       \
        bf16x8 af[4], bfr[4];                                                              \
        _Pragma("unroll")                                                                  \
        for (int m = 0; m < 4; ++m) {                                                      \
            int rw = wr + m * 16 + frow;                                                   \
            int kc = kk * 4 + fkc;                                                         \
            af[m] = *(const bf16x8*)(As + (size_t)((rw << 3) + (kc ^ (rw & 7))) * 8);      \
        }                                                                                  \
        _Pragma("unroll")                                                                  \
        for (int n = 0; n < 4; ++n) {                                                      \
            int rw = wc + n * 16 + frow;                                                   \
            int kc = kk * 4 + fkc;                                                         \
            bfr[n] = *(const bf16x8*)(&Bs[bufi][(size_t)((rw << 3) + (kc ^ (rw & 7))) * 8]); \
        }                                                                                  \
        _Pragma("unroll")                                                                  \
        for (int m = 0; m < 4; ++m)                                                        \
            _Pragma("unroll")                                                              \
            for (int n = 0; n < 4; ++n)                                                    \
                acc[m][n] = __builtin_amdgcn_mfma_f32_16x16x32_bf16(bfr[n], af[m], acc[m][n], 0, 0, 0); \
    } } while (0)

    const int nt = K >> 6;
    ALOAD(0);
    STAGE_B(0, 0);
    AWRITE();
    __syncthreads();
    for (int t = 0; t < nt; ++t) {
        if (t + 1 < nt) {
            ALOAD((t + 1) << 6);
            STAGE_B((t + 1) & 1, (t + 1) << 6);
        }
        COMPUTE(t & 1);
        __syncthreads();
        if (t + 1 < nt) AWRITE();
        __syncthreads();
    }
#undef ALOAD
#undef AWRITE
#undef STAGE_B
#undef COMPUTE

    const int ccol0 = (lane >> 4) << 2;
    #pragma unroll
    for (int m = 0; m < 4; ++m) {
        int row = bm + wr + m * 16 + frow;
        if (row < M) {
            #pragma unroll
            for (int n = 0; n < 4; ++n) {
                int col = bn + wc + n * 16 + ccol0;
                f32x4 v = acc[m][n];
                if (bias) {
                    v[0] += bias[col + 0];
                    v[1] += bias[col + 1];
                    v[2] += bias[col + 2];
                    v[3] += bias[col + 3];
                }
                if constexpr (OBF) {
                    ushort4 oo;
                    oo.x = f2bf(v[0]); oo.y = f2bf(v[1]); oo.z = f2bf(v[2]); oo.w = f2bf(v[3]);
                    *(ushort4*)((unsigned short*)sg.C + (size_t)row * ldc + col) = oo;
                } else {
                    *(float4*)((float*)sg.C + (size_t)row * ldc + col) = make_float4(v[0], v[1], v[2], v[3]);
                }
            }
        }
    }
}

// ---------------- merged CSR mean-aggregate: 16B/lane dual-edge gather ----------------
// One wave per node. Lanes 0-31 gather edge e's row (16B each), lanes 32-63 edge e+1's
// row -> 2 rows per load instruction. Per-dim partials combined once at the end via
// __shfl_xor(.,32). Indices prefetched lane-parallel (one vector load per 64 edges).
struct ASeg {
    const int* offsA; const int* csrA; const unsigned short* projA; int ldpA; const float* biasA;
    const int* offsB; const int* csrB; const unsigned short* projB; int ldpB; const float* biasB;
    unsigned short* outx; int ldo; int ndst; int blk0;
};
struct ABatch { ASeg s[3]; int b1, b2; };

__device__ __forceinline__ void agg_sum16(const int* __restrict__ csr, int beg, int end,
                                          const unsigned short* __restrict__ base, int ldp,
                                          int lane, float* __restrict__ s) {
    int half = lane >> 5;  // 0: even edge of pair, 1: odd edge
    for (int b = beg; b < end; b += 64) {
        int cnt = min(64, end - b);
        int myidx = csr[min(b + lane, end - 1)];
        int g = 0;
        for (; g + 3 < cnt; g += 4) {
            int i0 = __shfl(myidx, g + half);
            int i1 = __shfl(myidx, g + 2 + half);
            us8 u0 = *(const us8*)(base + (size_t)i0 * ldp);
            us8 u1 = *(const us8*)(base + (size_t)i1 * ldp);
            #pragma unroll
            for (int j = 0; j < 8; ++j) s[j] += bf2f(u0[j]) + bf2f(u1[j]);
        }
        for (; g + 1 < cnt; g += 2) {
            int i0 = __shfl(myidx, g + half);
            us8 u0 = *(const us8*)(base + (size_t)i0 * ldp);
            #pragma unroll
            for (int j = 0; j < 8; ++j) s[j] += bf2f(u0[j]);
        }
        if (g < cnt) {  // single tail edge: lower half only (upper half contributes 0)
            int i0 = __shfl(myidx, g);
            if (half == 0) {
                us8 u0 = *(const us8*)(base + (size_t)i0 * ldp);
                #pragma unroll
                for (int j = 0; j < 8; ++j) s[j] += bf2f(u0[j]);
            }
        }
    }
}

__global__ __launch_bounds__(256) void k_aggb(ABatch ab) {
    int b = blockIdx.x;
    int si = (b >= ab.b1) + (b >= ab.b2);
    const ASeg sg = ab.s[si];
    int node = (b - sg.blk0) * 4 + (threadIdx.x >> 6);
    int lane = threadIdx.x & 63;
    if (node >= sg.ndst) return;
    const int off = (lane & 31) * 8;   // dim offset (elements)

    float r[8];
    {
        float s[8] = {};
        int beg = sg.offsA[node], end = sg.offsA[node + 1];
        agg_sum16(sg.csrA, beg, end, sg.projA + off, sg.ldpA, lane, s);
        #pragma unroll
        for (int j = 0; j < 8; ++j) s[j] += __shfl_xor(s[j], 32);
        float inv = 1.f / fmaxf((float)(end - beg), 1.f);
        float4 b0 = *(const float4*)(sg.biasA + off);
        float4 b1 = *(const float4*)(sg.biasA + off + 4);
        r[0] = s[0] * inv + b0.x; r[1] = s[1] * inv + b0.y;
        r[2] = s[2] * inv + b0.z; r[3] = s[3] * inv + b0.w;
        r[4] = s[4] * inv + b1.x; r[5] = s[5] * inv + b1.y;
        r[6] = s[6] * inv + b1.z; r[7] = s[7] * inv + b1.w;
    }
    if (sg.csrB) {
        float s[8] = {};
        int beg = sg.offsB[node], end = sg.offsB[node + 1];
        agg_sum16(sg.csrB, beg, end, sg.projB + off, sg.ldpB, lane, s);
        #pragma unroll
        for (int j = 0; j < 8; ++j) s[j] += __shfl_xor(s[j], 32);
        float inv = 1.f / fmaxf((float)(end - beg), 1.f);
        float4 b0 = *(const float4*)(sg.biasB + off);
        float4 b1 = *(const float4*)(sg.biasB + off + 4);
        r[0] += s[0] * inv + b0.x; r[1] += s[1] * inv + b0.y;
        r[2] += s[2] * inv + b0.z; r[3] += s[3] * inv + b0.w;
        r[4] += s[4] * inv + b1.x; r[5] += s[5] * inv + b1.y;
        r[6] += s[6] * inv + b1.z; r[7] += s[7] * inv + b1.w;
    }

    if (lane < 32) {
        unsigned short* op = sg.outx + (size_t)node * sg.ldo + off;
        us8 cur = *(const us8*)op;
        us8 w;
        #pragma unroll
        for (int j = 0; j < 8; ++j) w[j] = f2bf(bf2f(cur[j]) + r[j]);
        *(us8*)op = w;
    }
}

// ---------------- cosine: one wave per row ----------------
__global__ __launch_bounds__(256) void k_cos(const float* __restrict__ ro,
                                             const float* __restrict__ pr,
                                             const int* __restrict__ types,
                                             float* __restrict__ out, int nr) {
    int row = blockIdx.x * 4 + (threadIdx.x >> 6);
    int lane = threadIdx.x & 63;
    if (row >= nr) return;
    int t = types[row];
    float2 r = ((const float2*)(ro + (size_t)row * OUTD_))[lane];
    float2 nn = ((const float2*)(pr + (size_t)row * 384 + t * OUTD_))[lane];
    float num = r.x * nn.x + r.y * nn.y;
    float d1 = r.x * r.x + r.y * r.y;
    float d2 = nn.x * nn.x + nn.y * nn.y;
    #pragma unroll
    for (int s = 1; s < 64; s <<= 1) {
        num += __shfl_xor(num, s);
        d1 += __shfl_xor(d1, s);
        d2 += __shfl_xor(d2, s);
    }
    if (lane == 0) out[row] = (num / fmaxf(sqrtf(d1) * sqrtf(d2), 1e-8f) + 1.f) * 0.5f;
}

extern "C" void kernel_launch(void* const* d_in, const int* in_sizes, int n_in,
                              void* d_out, int out_size, void* d_ws, size_t ws_size,
                              hipStream_t stream) {
    const float* x_r0 = (const float*)d_in[0];
    const float* x_p0 = (const float*)d_in[1];
    const float* x_m0 = (const float*)d_in[2];
    const int* e_src[4] = {(const int*)d_in[3], (const int*)d_in[5], (const int*)d_in[7], (const int*)d_in[9]};
    const int* e_dst[4] = {(const int*)d_in[4], (const int*)d_in[6], (const int*)d_in[8], (const int*)d_in[10]};
    const float* notes = (const float*)d_in[11];
    const int* types = (const int*)d_in[12];
    const float* Wl0 = (const float*)d_in[13];
    const float* Wr0 = (const float*)d_in[14];
    const float* bl0 = (const float*)d_in[15];
    const float* WlL = (const float*)d_in[16];
    const float* WrL = (const float*)d_in[17];
    const float* blL = (const float*)d_in[18];
    const float* Wre = (const float*)d_in[19];
    const float* bre = (const float*)d_in[20];
    const float* Wn  = (const float*)d_in[21];
    const float* bn  = (const float*)d_in[22];
    float* out = (float*)d_out;

    // ---- workspace carve ----
    uintptr_t base = (uintptr_t)d_ws;
    auto alloc = [&](size_t bytes) -> void* {
        uintptr_t p = (base + 255) & ~(uintptr_t)255;
        base = p + bytes;
        return (void*)p;
    };
    unsigned short* Rb[2] = {(unsigned short*)alloc((size_t)NR_ * 768 * 2),
                             (unsigned short*)alloc((size_t)NR_ * 768 * 2)};
    unsigned short* Pb[2] = {(unsigned short*)alloc((size_t)NP2_ * 512 * 2),
                             (unsigned short*)alloc((size_t)NP2_ * 512 * 2)};
    unsigned short* Mb[2] = {(unsigned short*)alloc((size_t)NM_ * 512 * 2),
                             (unsigned short*)alloc((size_t)NM_ * 512 * 2)};
    float* ro = (float*)alloc((size_t)NR_ * OUTD_ * 4);
    float* pr = (float*)alloc((size_t)NR_ * 384 * 4);
    unsigned short* wbf = (unsigned short*)alloc((size_t)4000000 * 2);
    int* csum = (int*)alloc(160 * 4);
    int nd[4] = {NR_, NR_, NP2_, NM_};
    Csr4 cs{};
    for (int t = 0; t < 4; ++t) {
        cs.src[t] = e_src[t]; cs.dst[t] = e_dst[t]; cs.n[t] = nd[t];
        cs.offs[t] = (int*)alloc(((size_t)nd[t] + 1) * 4);
        cs.cur[t]  = (int*)alloc((size_t)nd[t] * 4);
        cs.csr[t]  = (int*)alloc((size_t)NE_ * 4);
    }

    // ---- weight transpose+convert: concatenated B blocks, bf16 [N][K] ----
    unsigned short *BR[4], *BP[4], *BM[4], *Bre, *Bn;
    {
        WBatch wb{};
        int cnt = 0;
        size_t woff = 0;
        auto add = [&](const float* a, const float* bb, int K, int N) -> unsigned short* {
            unsigned short* dst = wbf + woff;
            woff += (size_t)K * N;
            wb.it[cnt] = WItem{a, bb, dst, K, N};
            ++cnt;
            return dst;
        };
        const size_t w0 = (size_t)EMB_ * HID_;
        const size_t wl = (size_t)HID_ * HID_;
        for (int l = 0; l < 4; ++l) {
            int K = (l == 0) ? EMB_ : HID_;
            const float* Wr_ = (l == 0) ? Wr0 : WrL + (size_t)(l - 1) * 4 * wl;
            const float* Wl_ = (l == 0) ? Wl0 : WlL + (size_t)(l - 1) * 4 * wl;
            size_t ws_ = (l == 0) ? w0 : wl;
            BR[l] = add(Wr_ + 0 * ws_, Wr_ + 1 * ws_, K, HID_);  // WrC
            add(Wl_ + 2 * ws_, nullptr, K, HID_);                 // Wl2 (r2p proj)
            add(Wl_ + 3 * ws_, nullptr, K, HID_);                 // Wl3 (r2m proj)
            BP[l] = add(Wr_ + 2 * ws_, nullptr, K, HID_);         // Wr2
            add(Wl_ + 0 * ws_, nullptr, K, HID_);                 // Wl0 (p2r proj)
            BM[l] = add(Wr_ + 3 * ws_, nullptr, K, HID_);         // Wr3
            add(Wl_ + 1 * ws_, nullptr, K, HID_);                 // Wl1 (m2r proj)
        }
        Bre = add(Wre, nullptr, HID_, OUTD_);
        Bn = add(Wn + 0 * (size_t)EMB_ * OUTD_, nullptr, EMB_, OUTD_);
        add(Wn + 1 * (size_t)EMB_ * OUTD_, nullptr, EMB_, OUTD_);
        add(Wn + 2 * (size_t)EMB_ * OUTD_, nullptr, EMB_, OUTD_);
        k_wconvT<<<dim3(128, cnt), 256, 0, stream>>>(wb);
    }

    // ---- CSR build (batched over the 4 edge types) ----
    k_zero4<<<dim3((NP2_ + 255) / 256, 4), 256, 0, stream>>>(cs);
    k_deg4<<<dim3((NE_ + 255) / 256, 4), 256, 0, stream>>>(cs);
    k_scanA<<<dim3(40, 4), 256, 0, stream>>>(cs, csum);
    k_scanB<<<1, 64, 0, stream>>>(cs, csum);
    k_scanC<<<dim3((NP2_ + 255) / 256, 4), 256, 0, stream>>>(cs, csum);
    k_scatter4<<<dim3((NE_ + 255) / 256, 4), 256, 0, stream>>>(cs);

    const int MT_R = (NR_ + 127) / 128;    // 128
    const int MT_P = (NP2_ + 127) / 128;   // 313
    const int MT_M = (NM_ + 127) / 128;    // 235
    auto seg = [](const void* A, const unsigned short* Bt, void* C, const float* bias,
                  int lda, int ldc, int M, int K, int ntn, int blk0) -> GSeg {
        return GSeg{A, Bt, C, bias, lda, ldc, M, K, ntn, blk0};
    };

    const int AB_R = (NR_ + 3) / 4, AB_P = (NP2_ + 3) / 4, AB_M = (NM_ + 3) / 4;

    for (int l = 0; l < 4; ++l) {
        int K = (l == 0) ? EMB_ : HID_;
        unsigned short* R = Rb[l & 1];
        unsigned short* P = Pb[l & 1];
        unsigned short* M = Mb[l & 1];
        const float* bl_ = (l == 0) ? bl0 : blL + (size_t)(l - 1) * 4 * HID_;

        GBatch gb{};
        int nR = MT_R * 6, nP = MT_P * 4, nM = MT_M * 4;
        if (l == 0) {
            gb.s[0] = seg(x_r0, BR[0], R, nullptr, EMB_, 768, NR_, EMB_, 6, 0);
            gb.s[1] = seg(x_p0, BP[0], P, nullptr, EMB_, 512, NP2_, EMB_, 4, nR);
            gb.s[2] = seg(x_m0, BM[0], M, nullptr, EMB_, 512, NM_, EMB_, 4, nR + nP);
        } else {
            gb.s[0] = seg(Rb[(l - 1) & 1], BR[l], R, nullptr, 768, 768, NR_, K, 6, 0);
            gb.s[1] = seg(Pb[(l - 1) & 1], BP[l], P, nullptr, 512, 512, NP2_, K, 4, nR);
            gb.s[2] = seg(Mb[(l - 1) & 1], BM[l], M, nullptr, 512, 512, NM_, K, 4, nR + nP);
        }
        gb.b1 = nR; gb.b2 = nR + nP; gb.tot = nR + nP + nM;
        if (l == 0) k_gemma<true><<<gb.tot, 256, 0, stream>>>(gb);
        else        k_gemmb<true><<<gb.tot, 256, 0, stream>>>(gb);

        // merged aggregates: reaction (p2r + m2r), protein (r2p), molecule (r2m)
        ABatch ab{};
        ab.s[0] = ASeg{cs.offs[0], cs.csr[0], P + 256, 512, bl_ + 0 * HID_,
                       cs.offs[1], cs.csr[1], M + 256, 512, bl_ + 1 * HID_,
                       R, 768, NR_, 0};
        ab.s[1] = ASeg{cs.offs[2], cs.csr[2], R + 256, 768, bl_ + 2 * HID_,
                       nullptr, nullptr, nullptr, 0, nullptr,
                       P, 512, NP2_, AB_R};
        ab.s[2] = ASeg{cs.offs[3], cs.csr[3], R + 512, 768, bl_ + 3 * HID_,
                       nullptr, nullptr, nullptr, 0, nullptr,
                       M, 512, NM_, AB_R + AB_P};
        ab.b1 = AB_R; ab.b2 = AB_R + AB_P;
        k_aggb<<<AB_R + AB_P + AB_M, 256, 0, stream>>>(ab);
    }

    // ---- finale: reaction proj (bf16-A) + notes projs (f32-A pipelined) + cosine ----
    {
        GBatch g1{};
        g1.s[0] = seg(Rb[1], Bre, ro, bre, 768, OUTD_, NR_, HID_, 1, 0);
        g1.b1 = g1.b2 = g1.tot = MT_R;
        k_gemmb<false><<<g1.tot, 256, 0, stream>>>(g1);
        GBatch g2{};
        g2.s[0] = seg(notes, Bn, pr, bn, EMB_, 384, NR_, EMB_, 3, 0);
        g2.b1 = g2.b2 = g2.tot = MT_R * 3;
        k_gemma<false><<<g2.tot, 256, 0, stream>>>(g2);
    }
    k_cos<<<NR_ / 4, 256, 0, stream>>>(ro, pr, types, out, NR_);
}

// Round 16
// 745.993 us; speedup vs baseline: 2.9498x; 1.0018x over previous
//
#include <hip/hip_runtime.h>
#include <hip/hip_bf16.h>
#include <math.h>
#include <stdint.h>

#define NR_ 16384
#define NP2_ 40000
#define NM_ 30000
#define NE_ 200000
#define EMB_ 1024
#define HID_ 256
#define OUTD_ 128

typedef __attribute__((ext_vector_type(8))) short bf16x8;
typedef __attribute__((ext_vector_type(4))) float f32x4;
typedef __attribute__((ext_vector_type(8))) unsigned short us8;

// hardware-path f32->bf16 (RNE): plain cast lets the compiler emit v_cvt_pk_bf16_f32
__device__ __forceinline__ unsigned short f2bf(float f) {
    return __builtin_bit_cast(unsigned short, __float2bfloat16(f));
}
__device__ __forceinline__ float bf2f(unsigned short u) {
    uint32_t v = ((uint32_t)u) << 16;
    return __builtin_bit_cast(float, v);
}

// ---------------- batched CSR build ----------------
struct Csr4 {
    const int* src[4]; const int* dst[4];
    int* offs[4]; int* cur[4]; int* csr[4];
    int n[4];
};
__global__ void k_zero4(Csr4 c) {
    int y = blockIdx.y;
    int i = blockIdx.x * 256 + threadIdx.x;
    if (i < c.n[y]) c.cur[y][i] = 0;
}
__global__ void k_deg4(Csr4 c) {
    int y = blockIdx.y;
    int i = blockIdx.x * 256 + threadIdx.x;
    if (i < NE_) atomicAdd(&c.cur[y][c.dst[y][i]], 1);
}
__global__ void k_scanA(Csr4 c, int* __restrict__ csum) {
    int y = blockIdx.y;
    int n = c.n[y];
    int ch = blockIdx.x;
    int nch = (n + 1023) >> 10;
    if (ch >= nch) return;
    const int* deg = c.cur[y];
    int* offs = c.offs[y];
    __shared__ int ts[256];
    int base = ch << 10;
    int t = threadIdx.x;
    int v[4];
    int s = 0;
    #pragma unroll
    for (int k = 0; k < 4; ++k) {
        int i = base + t * 4 + k;
        v[k] = (i < n) ? deg[i] : 0;
        s += v[k];
    }
    ts[t] = s;
    __syncthreads();
    for (int st = 1; st < 256; st <<= 1) {
        int x = ts[t];
        int xo = (t >= st) ? ts[t - st] : 0;
        __syncthreads();
        ts[t] = x + xo;
        __syncthreads();
    }
    int run = (t > 0) ? ts[t - 1] : 0;
    #pragma unroll
    for (int k = 0; k < 4; ++k) {
        int i = base + t * 4 + k;
        if (i < n) offs[i] = run;
        run += v[k];
    }
    if (t == 255) csum[y * 40 + ch] = ts[255];
}
__global__ void k_scanB(Csr4 c, int* __restrict__ csum) {
    int y = threadIdx.x;
    if (y < 4) {
        int n = c.n[y];
        int nch = (n + 1023) >> 10;
        int acc = 0;
        for (int i = 0; i < nch; ++i) {
            int v = csum[y * 40 + i];
            csum[y * 40 + i] = acc;
            acc += v;
        }
        c.offs[y][n] = acc;
    }
}
__global__ void k_scanC(Csr4 c, const int* __restrict__ csum) {
    int y = blockIdx.y;
    int i = blockIdx.x * 256 + threadIdx.x;
    if (i < c.n[y]) {
        int v = c.offs[y][i] + csum[y * 40 + (i >> 10)];
        c.offs[y][i] = v;
        c.cur[y][i] = v;
    }
}
__global__ void k_scatter4(Csr4 c) {
    int y = blockIdx.y;
    int i = blockIdx.x * 256 + threadIdx.x;
    if (i < NE_) {
        int d = c.dst[y][i];
        int p = atomicAdd(&c.cur[y][d], 1);
        c.csr[y][p] = c.src[y][i];
    }
}

// batched weight transpose+convert: dst[n*K+k] = bf16(a[k*N+n] (+ b[k*N+n]))
struct WItem { const float* a; const float* b; unsigned short* dst; int k; int n; };
struct WBatch { WItem it[32]; };
__global__ void k_wconvT(WBatch wb) {
    WItem w = wb.it[blockIdx.y];
    int total = w.k * w.n;
    int kmask = w.k - 1;
    int shift = (w.k == 1024) ? 10 : 8;
    for (int idx = blockIdx.x * 256 + threadIdx.x; idx < total; idx += gridDim.x * 256) {
        int k = idx & kmask, n = idx >> shift;
        float v = w.a[(size_t)k * w.n + n];
        if (w.b) v += w.b[(size_t)k * w.n + n];
        w.dst[idx] = f2bf(v);
    }
}

struct GSeg {
    const void* A; const unsigned short* Bt; void* C; const float* bias;
    int lda, ldc, M, K, ntn, blk0;
};
struct GBatch { GSeg s[3]; int b1, b2, tot; };

// ---------------- bf16-A batched MFMA GEMM (round-8 proven core, bounds 256,3) ----------------
template <bool OBF>
__global__ __launch_bounds__(256, 3) void k_gemmb(GBatch gb) {
    __shared__ __align__(16) unsigned short As[128 * 64];
    __shared__ __align__(16) unsigned short Bs[128 * 64];
    const int tid = threadIdx.x;
    const int lane = tid & 63;
    int nwg = gb.tot;
    int o = blockIdx.x;
    int q = nwg >> 3, r = nwg & 7;
    int xcd = o & 7, j = o >> 3;
    int wg = (xcd < r ? xcd * (q + 1) : r * (q + 1) + (xcd - r) * q) + j;
    const int si = (wg >= gb.b1) + (wg >= gb.b2);
    const GSeg sg = gb.s[si];
    const int local = wg - sg.blk0;
    const int bm = (local / sg.ntn) * 128;
    const int bn = (local % sg.ntn) * 128;
    const int lda = sg.lda, ldc = sg.ldc, M = sg.M, K = sg.K;
    const unsigned short* __restrict__ Bt = sg.Bt;
    const float* __restrict__ bias = sg.bias;

    const int wave = tid >> 6;
    const int wr = (wave >> 1) * 64;
    const int wc = (wave & 1) * 64;
    const int frow = lane & 15;
    const int fkc = lane >> 4;
    f32x4 acc[4][4] = {};

    for (int k0 = 0; k0 < K; k0 += 64) {
        #pragma unroll
        for (int i = 0; i < 4; ++i) {
            int c = tid + i * 256;
            int row = c >> 3, kc = c & 7;
            int srck = k0 + ((kc ^ (row & 7)) << 3);
            int ga = min(bm + row, M - 1);
            __builtin_amdgcn_global_load_lds(
                (const __attribute__((address_space(1))) unsigned int*)((const unsigned short*)sg.A + (size_t)ga * lda + srck),
                (__attribute__((address_space(3))) unsigned int*)(As + (size_t)c * 8), 16, 0, 0);
            __builtin_amdgcn_global_load_lds(
                (const __attribute__((address_space(1))) unsigned int*)(Bt + (size_t)(bn + row) * K + srck),
                (__attribute__((address_space(3))) unsigned int*)(Bs + (size_t)c * 8), 16, 0, 0);
        }
        __syncthreads();
        #pragma unroll
        for (int kk = 0; kk < 2; ++kk) {
            bf16x8 af[4], bfr[4];
            #pragma unroll
            for (int m = 0; m < 4; ++m) {
                int row = wr + m * 16 + frow;
                int kc = kk * 4 + fkc;
                af[m] = *(const bf16x8*)(As + (size_t)((row << 3) + (kc ^ (row & 7))) * 8);
            }
            #pragma unroll
            for (int n = 0; n < 4; ++n) {
                int row = wc + n * 16 + frow;
                int kc = kk * 4 + fkc;
                bfr[n] = *(const bf16x8*)(Bs + (size_t)((row << 3) + (kc ^ (row & 7))) * 8);
            }
            #pragma unroll
            for (int m = 0; m < 4; ++m)
                #pragma unroll
                for (int n = 0; n < 4; ++n)
                    acc[m][n] = __builtin_amdgcn_mfma_f32_16x16x32_bf16(bfr[n], af[m], acc[m][n], 0, 0, 0);
        }
        __syncthreads();
    }

    const int ccol0 = (lane >> 4) << 2;
    #pragma unroll
    for (int m = 0; m < 4; ++m) {
        int row = bm + wr + m * 16 + frow;
        if (row < M) {
            #pragma unroll
            for (int n = 0; n < 4; ++n) {
                int col = bn + wc + n * 16 + ccol0;
                f32x4 v = acc[m][n];
                if (bias) {
                    v[0] += bias[col + 0];
                    v[1] += bias[col + 1];
                    v[2] += bias[col + 2];
                    v[3] += bias[col + 3];
                }
                if constexpr (OBF) {
                    ushort4 oo;
                    oo.x = f2bf(v[0]); oo.y = f2bf(v[1]); oo.z = f2bf(v[2]); oo.w = f2bf(v[3]);
                    *(ushort4*)((unsigned short*)sg.C + (size_t)row * ldc + col) = oo;
                } else {
                    *(float4*)((float*)sg.C + (size_t)row * ldc + col) = make_float4(v[0], v[1], v[2], v[3]);
                }
            }
        }
    }
}

// ---------------- f32-A pipelined MFMA GEMM: counted-vmcnt 2-phase (T4) ----------------
// Per iter: issue ALOAD(t+1) [8 vm loads] then STAGE_B(t+1) [4 gload_lds] -> wait
// vmcnt(12) (retires exactly the 4 oldest = B(t)'s stages) -> s_barrier -> COMPUTE ->
// lgkmcnt(0) + s_barrier -> AWRITE (compiler waits vmcnt(4) for A-regs, B(t+1) stays
// in flight). vmcnt never drains to 0 inside the loop. asm memory clobbers pin all
// loads before the waits; sched_barrier(0) fences MFMA hoisting (rule #18).
template <bool OBF>
__global__ __launch_bounds__(256, 3) void k_gemma(GBatch gb) {
    __shared__ __align__(16) unsigned short As[128 * 64];
    __shared__ __align__(16) unsigned short Bs[2][128 * 64];
    const int tid = threadIdx.x;
    const int lane = tid & 63;
    int nwg = gb.tot;
    int o = blockIdx.x;
    int q = nwg >> 3, r = nwg & 7;
    int xcd = o & 7, j = o >> 3;
    int wg = (xcd < r ? xcd * (q + 1) : r * (q + 1) + (xcd - r) * q) + j;
    const int si = (wg >= gb.b1) + (wg >= gb.b2);
    const GSeg sg = gb.s[si];
    const int local = wg - sg.blk0;
    const int bm = (local / sg.ntn) * 128;
    const int bn = (local % sg.ntn) * 128;
    const int lda = sg.lda, ldc = sg.ldc, M = sg.M, K = sg.K;
    const unsigned short* __restrict__ Bt = sg.Bt;
    const float* __restrict__ bias = sg.bias;

    const int wave = tid >> 6;
    const int wr = (wave >> 1) * 64;
    const int wc = (wave & 1) * 64;
    const int frow = lane & 15;
    const int fkc = lane >> 4;
    f32x4 acc[4][4] = {};
    float4 ra0[4], ra1[4];

#define ALOAD(kk0) do {                                                                    \
    _Pragma("unroll")                                                                      \
    for (int i = 0; i < 4; ++i) {                                                          \
        int c = tid + i * 256, rw = c >> 3, kc = c & 7;                                    \
        int srck = (kk0) + ((kc ^ (rw & 7)) << 3);                                         \
        int ga = min(bm + rw, M - 1);                                                      \
        const float* Af = (const float*)sg.A + (size_t)ga * lda + srck;                    \
        ra0[i] = *(const float4*)Af;                                                       \
        ra1[i] = *(const float4*)(Af + 4);                                                 \
    } } while (0)

#define AWRITE() do {                                                                      \
    _Pragma("unroll")                                                                      \
    for (int i = 0; i < 4; ++i) {                                                          \
        int c = tid + i * 256;                                                             \
        us8 oo;                                                                            \
        oo[0] = f2bf(ra0[i].x); oo[1] = f2bf(ra0[i].y);                                    \
        oo[2] = f2bf(ra0[i].z); oo[3] = f2bf(ra0[i].w);                                    \
        oo[4] = f2bf(ra1[i].x); oo[5] = f2bf(ra1[i].y);                                    \
        oo[6] = f2bf(ra1[i].z); oo[7] = f2bf(ra1[i].w);                                    \
        *(us8*)(As + (size_t)c * 8) = oo;                                                  \
    } } while (0)

#define STAGE_B(bufi, kk0) do {                                                            \
    _Pragma("unroll")                                                                      \
    for (int i = 0; i < 4; ++i) {                                                          \
        int c = tid + i * 256, rw = c >> 3, kc = c & 7;                                    \
        int srck = (kk0) + ((kc ^ (rw & 7)) << 3);                                         \
        __builtin_amdgcn_global_load_lds(                                                  \
            (const __attribute__((address_space(1))) unsigned int*)(Bt + (size_t)(bn + rw) * K + srck), \
            (__attribute__((address_space(3))) unsigned int*)(&Bs[bufi][(size_t)c * 8]), 16, 0, 0); \
    } } while (0)

#define COMPUTE(bufi) do {                                                                 \
    _Pragma("unroll")                                                                      \
    for (int kk = 0; kk < 2; ++kk) {                                                       \
        bf16x8 af[4], bfr[4];                                                              \
        _Pragma("unroll")                                                                  \
        for (int m = 0; m < 4; ++m) {                                                      \
            int rw = wr + m * 16 + frow;                                                   \
            int kc = kk * 4 + fkc;                                                         \
            af[m] = *(const bf16x8*)(As + (size_t)((rw << 3) + (kc ^ (rw & 7))) * 8);      \
        }                                                                                  \
        _Pragma("unroll")                                                                  \
        for (int n = 0; n < 4; ++n) {                                                      \
            int rw = wc + n * 16 + frow;                                                   \
            int kc = kk * 4 + fkc;                                                         \
            bfr[n] = *(const bf16x8*)(&Bs[bufi][(size_t)((rw << 3) + (kc ^ (rw & 7))) * 8]); \
        }                                                                                  \
        _Pragma("unroll")                                                                  \
        for (int m = 0; m < 4; ++m)                                                        \
            _Pragma("unroll")                                                              \
            for (int n = 0; n < 4; ++n)                                                    \
                acc[m][n] = __builtin_amdgcn_mfma_f32_16x16x32_bf16(bfr[n], af[m], acc[m][n], 0, 0, 0); \
    } } while (0)

    const int nt = K >> 6;
    // prologue: stage tile 0; outstanding after = [B4_0]
    ALOAD(0);
    STAGE_B(0, 0);
    AWRITE();   // compiler inserts vmcnt wait for the 8 A-loads (B stays in flight)
    asm volatile("s_waitcnt lgkmcnt(0)" ::: "memory");
    __builtin_amdgcn_sched_barrier(0);
    for (int t = 0; t < nt; ++t) {
        if (t + 1 < nt) {
            ALOAD((t + 1) << 6);            // +8 (oldest of this iter's issues)
            STAGE_B((t + 1) & 1, (t + 1) << 6);  // +4
            asm volatile("s_waitcnt vmcnt(12)" ::: "memory");  // retire B4_t
        } else {
            asm volatile("s_waitcnt vmcnt(0)" ::: "memory");   // tail: drain B4_t
        }
        __builtin_amdgcn_s_barrier();       // Bs[t&1] + As(t) valid for all waves
        __builtin_amdgcn_sched_barrier(0);
        COMPUTE(t & 1);
        asm volatile("s_waitcnt lgkmcnt(0)" ::: "memory");  // my ds_reads of As done
        __builtin_amdgcn_s_barrier();       // all waves done reading As
        __builtin_amdgcn_sched_barrier(0);
        if (t + 1 < nt) {
            AWRITE();                       // waits vmcnt(4): A-regs ready, B4_{t+1} in flight
            asm volatile("s_waitcnt lgkmcnt(0)" ::: "memory");
            __builtin_amdgcn_sched_barrier(0);
        }
    }
#undef ALOAD
#undef AWRITE
#undef STAGE_B
#undef COMPUTE

    const int ccol0 = (lane >> 4) << 2;
    #pragma unroll
    for (int m = 0; m < 4; ++m) {
        int row = bm + wr + m * 16 + frow;
        if (row < M) {
            #pragma unroll
            for (int n = 0; n < 4; ++n) {
                int col = bn + wc + n * 16 + ccol0;
                f32x4 v = acc[m][n];
                if (bias) {
                    v[0] += bias[col + 0];
                    v[1] += bias[col + 1];
                    v[2] += bias[col + 2];
                    v[3] += bias[col + 3];
                }
                if constexpr (OBF) {
                    ushort4 oo;
                    oo.x = f2bf(v[0]); oo.y = f2bf(v[1]); oo.z = f2bf(v[2]); oo.w = f2bf(v[3]);
                    *(ushort4*)((unsigned short*)sg.C + (size_t)row * ldc + col) = oo;
                } else {
                    *(float4*)((float*)sg.C + (size_t)row * ldc + col) = make_float4(v[0], v[1], v[2], v[3]);
                }
            }
        }
    }
}

// ---------------- merged CSR mean-aggregate: 16B/lane dual-edge gather ----------------
struct ASeg {
    const int* offsA; const int* csrA; const unsigned short* projA; int ldpA; const float* biasA;
    const int* offsB; const int* csrB; const unsigned short* projB; int ldpB; const float* biasB;
    unsigned short* outx; int ldo; int ndst; int blk0;
};
struct ABatch { ASeg s[3]; int b1, b2; };

__device__ __forceinline__ void agg_sum16(const int* __restrict__ csr, int beg, int end,
                                          const unsigned short* __restrict__ base, int ldp,
                                          int lane, float* __restrict__ s) {
    int half = lane >> 5;  // 0: even edge of pair, 1: odd edge
    for (int b = beg; b < end; b += 64) {
        int cnt = min(64, end - b);
        int myidx = csr[min(b + lane, end - 1)];
        int g = 0;
        for (; g + 3 < cnt; g += 4) {
            int i0 = __shfl(myidx, g + half);
            int i1 = __shfl(myidx, g + 2 + half);
            us8 u0 = *(const us8*)(base + (size_t)i0 * ldp);
            us8 u1 = *(const us8*)(base + (size_t)i1 * ldp);
            #pragma unroll
            for (int j = 0; j < 8; ++j) s[j] += bf2f(u0[j]) + bf2f(u1[j]);
        }
        for (; g + 1 < cnt; g += 2) {
            int i0 = __shfl(myidx, g + half);
            us8 u0 = *(const us8*)(base + (size_t)i0 * ldp);
            #pragma unroll
            for (int j = 0; j < 8; ++j) s[j] += bf2f(u0[j]);
        }
        if (g < cnt) {  // single tail edge: lower half only
            int i0 = __shfl(myidx, g);
            if (half == 0) {
                us8 u0 = *(const us8*)(base + (size_t)i0 * ldp);
                #pragma unroll
                for (int j = 0; j < 8; ++j) s[j] += bf2f(u0[j]);
            }
        }
    }
}

__global__ __launch_bounds__(256) void k_aggb(ABatch ab) {
    int b = blockIdx.x;
    int si = (b >= ab.b1) + (b >= ab.b2);
    const ASeg sg = ab.s[si];
    int node = (b - sg.blk0) * 4 + (threadIdx.x >> 6);
    int lane = threadIdx.x & 63;
    if (node >= sg.ndst) return;
    const int off = (lane & 31) * 8;   // dim offset (elements)

    float r[8];
    {
        float s[8] = {};
        int beg = sg.offsA[node], end = sg.offsA[node + 1];
        agg_sum16(sg.csrA, beg, end, sg.projA + off, sg.ldpA, lane, s);
        #pragma unroll
        for (int j = 0; j < 8; ++j) s[j] += __shfl_xor(s[j], 32);
        float inv = 1.f / fmaxf((float)(end - beg), 1.f);
        float4 b0 = *(const float4*)(sg.biasA + off);
        float4 b1 = *(const float4*)(sg.biasA + off + 4);
        r[0] = s[0] * inv + b0.x; r[1] = s[1] * inv + b0.y;
        r[2] = s[2] * inv + b0.z; r[3] = s[3] * inv + b0.w;
        r[4] = s[4] * inv + b1.x; r[5] = s[5] * inv + b1.y;
        r[6] = s[6] * inv + b1.z; r[7] = s[7] * inv + b1.w;
    }
    if (sg.csrB) {
        float s[8] = {};
        int beg = sg.offsB[node], end = sg.offsB[node + 1];
        agg_sum16(sg.csrB, beg, end, sg.projB + off, sg.ldpB, lane, s);
        #pragma unroll
        for (int j = 0; j < 8; ++j) s[j] += __shfl_xor(s[j], 32);
        float inv = 1.f / fmaxf((float)(end - beg), 1.f);
        float4 b0 = *(const float4*)(sg.biasB + off);
        float4 b1 = *(const float4*)(sg.biasB + off + 4);
        r[0] += s[0] * inv + b0.x; r[1] += s[1] * inv + b0.y;
        r[2] += s[2] * inv + b0.z; r[3] += s[3] * inv + b0.w;
        r[4] += s[4] * inv + b1.x; r[5] += s[5] * inv + b1.y;
        r[6] += s[6] * inv + b1.z; r[7] += s[7] * inv + b1.w;
    }

    if (lane < 32) {
        unsigned short* op = sg.outx + (size_t)node * sg.ldo + off;
        us8 cur = *(const us8*)op;
        us8 w;
        #pragma unroll
        for (int j = 0; j < 8; ++j) w[j] = f2bf(bf2f(cur[j]) + r[j]);
        *(us8*)op = w;
    }
}

// ---------------- cosine: one wave per row ----------------
__global__ __launch_bounds__(256) void k_cos(const float* __restrict__ ro,
                                             const float* __restrict__ pr,
                                             const int* __restrict__ types,
                                             float* __restrict__ out, int nr) {
    int row = blockIdx.x * 4 + (threadIdx.x >> 6);
    int lane = threadIdx.x & 63;
    if (row >= nr) return;
    int t = types[row];
    float2 r = ((const float2*)(ro + (size_t)row * OUTD_))[lane];
    float2 nn = ((const float2*)(pr + (size_t)row * 384 + t * OUTD_))[lane];
    float num = r.x * nn.x + r.y * nn.y;
    float d1 = r.x * r.x + r.y * r.y;
    float d2 = nn.x * nn.x + nn.y * nn.y;
    #pragma unroll
    for (int s = 1; s < 64; s <<= 1) {
        num += __shfl_xor(num, s);
        d1 += __shfl_xor(d1, s);
        d2 += __shfl_xor(d2, s);
    }
    if (lane == 0) out[row] = (num / fmaxf(sqrtf(d1) * sqrtf(d2), 1e-8f) + 1.f) * 0.5f;
}

extern "C" void kernel_launch(void* const* d_in, const int* in_sizes, int n_in,
                              void* d_out, int out_size, void* d_ws, size_t ws_size,
                              hipStream_t stream) {
    const float* x_r0 = (const float*)d_in[0];
    const float* x_p0 = (const float*)d_in[1];
    const float* x_m0 = (const float*)d_in[2];
    const int* e_src[4] = {(const int*)d_in[3], (const int*)d_in[5], (const int*)d_in[7], (const int*)d_in[9]};
    const int* e_dst[4] = {(const int*)d_in[4], (const int*)d_in[6], (const int*)d_in[8], (const int*)d_in[10]};
    const float* notes = (const float*)d_in[11];
    const int* types = (const int*)d_in[12];
    const float* Wl0 = (const float*)d_in[13];
    const float* Wr0 = (const float*)d_in[14];
    const float* bl0 = (const float*)d_in[15];
    const float* WlL = (const float*)d_in[16];
    const float* WrL = (const float*)d_in[17];
    const float* blL = (const float*)d_in[18];
    const float* Wre = (const float*)d_in[19];
    const float* bre = (const float*)d_in[20];
    const float* Wn  = (const float*)d_in[21];
    const float* bn  = (const float*)d_in[22];
    float* out = (float*)d_out;

    // ---- workspace carve ----
    uintptr_t base = (uintptr_t)d_ws;
    auto alloc = [&](size_t bytes) -> void* {
        uintptr_t p = (base + 255) & ~(uintptr_t)255;
        base = p + bytes;
        return (void*)p;
    };
    unsigned short* Rb[2] = {(unsigned short*)alloc((size_t)NR_ * 768 * 2),
                             (unsigned short*)alloc((size_t)NR_ * 768 * 2)};
    unsigned short* Pb[2] = {(unsigned short*)alloc((size_t)NP2_ * 512 * 2),
                             (unsigned short*)alloc((size_t)NP2_ * 512 * 2)};
    unsigned short* Mb[2] = {(unsigned short*)alloc((size_t)NM_ * 512 * 2),
                             (unsigned short*)alloc((size_t)NM_ * 512 * 2)};
    float* ro = (float*)alloc((size_t)NR_ * OUTD_ * 4);
    float* pr = (float*)alloc((size_t)NR_ * 384 * 4);
    unsigned short* wbf = (unsigned short*)alloc((size_t)4000000 * 2);
    int* csum = (int*)alloc(160 * 4);
    int nd[4] = {NR_, NR_, NP2_, NM_};
    Csr4 cs{};
    for (int t = 0; t < 4; ++t) {
        cs.src[t] = e_src[t]; cs.dst[t] = e_dst[t]; cs.n[t] = nd[t];
        cs.offs[t] = (int*)alloc(((size_t)nd[t] + 1) * 4);
        cs.cur[t]  = (int*)alloc((size_t)nd[t] * 4);
        cs.csr[t]  = (int*)alloc((size_t)NE_ * 4);
    }

    // ---- weight transpose+convert: concatenated B blocks, bf16 [N][K] ----
    unsigned short *BR[4], *BP[4], *BM[4], *Bre, *Bn;
    {
        WBatch wb{};
        int cnt = 0;
        size_t woff = 0;
        auto add = [&](const float* a, const float* bb, int K, int N) -> unsigned short* {
            unsigned short* dst = wbf + woff;
            woff += (size_t)K * N;
            wb.it[cnt] = WItem{a, bb, dst, K, N};
            ++cnt;
            return dst;
        };
        const size_t w0 = (size_t)EMB_ * HID_;
        const size_t wl = (size_t)HID_ * HID_;
        for (int l = 0; l < 4; ++l) {
            int K = (l == 0) ? EMB_ : HID_;
            const float* Wr_ = (l == 0) ? Wr0 : WrL + (size_t)(l - 1) * 4 * wl;
            const float* Wl_ = (l == 0) ? Wl0 : WlL + (size_t)(l - 1) * 4 * wl;
            size_t ws_ = (l == 0) ? w0 : wl;
            BR[l] = add(Wr_ + 0 * ws_, Wr_ + 1 * ws_, K, HID_);  // WrC
            add(Wl_ + 2 * ws_, nullptr, K, HID_);                 // Wl2 (r2p proj)
            add(Wl_ + 3 * ws_, nullptr, K, HID_);                 // Wl3 (r2m proj)
            BP[l] = add(Wr_ + 2 * ws_, nullptr, K, HID_);         // Wr2
            add(Wl_ + 0 * ws_, nullptr, K, HID_);                 // Wl0 (p2r proj)
            BM[l] = add(Wr_ + 3 * ws_, nullptr, K, HID_);         // Wr3
            add(Wl_ + 1 * ws_, nullptr, K, HID_);                 // Wl1 (m2r proj)
        }
        Bre = add(Wre, nullptr, HID_, OUTD_);
        Bn = add(Wn + 0 * (size_t)EMB_ * OUTD_, nullptr, EMB_, OUTD_);
        add(Wn + 1 * (size_t)EMB_ * OUTD_, nullptr, EMB_, OUTD_);
        add(Wn + 2 * (size_t)EMB_ * OUTD_, nullptr, EMB_, OUTD_);
        k_wconvT<<<dim3(128, cnt), 256, 0, stream>>>(wb);
    }

    // ---- CSR build (batched over the 4 edge types) ----
    k_zero4<<<dim3((NP2_ + 255) / 256, 4), 256, 0, stream>>>(cs);
    k_deg4<<<dim3((NE_ + 255) / 256, 4), 256, 0, stream>>>(cs);
    k_scanA<<<dim3(40, 4), 256, 0, stream>>>(cs, csum);
    k_scanB<<<1, 64, 0, stream>>>(cs, csum);
    k_scanC<<<dim3((NP2_ + 255) / 256, 4), 256, 0, stream>>>(cs, csum);
    k_scatter4<<<dim3((NE_ + 255) / 256, 4), 256, 0, stream>>>(cs);

    const int MT_R = (NR_ + 127) / 128;    // 128
    const int MT_P = (NP2_ + 127) / 128;   // 313
    const int MT_M = (NM_ + 127) / 128;    // 235
    auto seg = [](const void* A, const unsigned short* Bt, void* C, const float* bias,
                  int lda, int ldc, int M, int K, int ntn, int blk0) -> GSeg {
        return GSeg{A, Bt, C, bias, lda, ldc, M, K, ntn, blk0};
    };

    const int AB_R = (NR_ + 3) / 4, AB_P = (NP2_ + 3) / 4, AB_M = (NM_ + 3) / 4;

    for (int l = 0; l < 4; ++l) {
        int K = (l == 0) ? EMB_ : HID_;
        unsigned short* R = Rb[l & 1];
        unsigned short* P = Pb[l & 1];
        unsigned short* M = Mb[l & 1];
        const float* bl_ = (l == 0) ? bl0 : blL + (size_t)(l - 1) * 4 * HID_;

        GBatch gb{};
        int nR = MT_R * 6, nP = MT_P * 4, nM = MT_M * 4;
        if (l == 0) {
            gb.s[0] = seg(x_r0, BR[0], R, nullptr, EMB_, 768, NR_, EMB_, 6, 0);
            gb.s[1] = seg(x_p0, BP[0], P, nullptr, EMB_, 512, NP2_, EMB_, 4, nR);
            gb.s[2] = seg(x_m0, BM[0], M, nullptr, EMB_, 512, NM_, EMB_, 4, nR + nP);
        } else {
            gb.s[0] = seg(Rb[(l - 1) & 1], BR[l], R, nullptr, 768, 768, NR_, K, 6, 0);
            gb.s[1] = seg(Pb[(l - 1) & 1], BP[l], P, nullptr, 512, 512, NP2_, K, 4, nR);
            gb.s[2] = seg(Mb[(l - 1) & 1], BM[l], M, nullptr, 512, 512, NM_, K, 4, nR + nP);
        }
        gb.b1 = nR; gb.b2 = nR + nP; gb.tot = nR + nP + nM;
        if (l == 0) k_gemma<true><<<gb.tot, 256, 0, stream>>>(gb);
        else        k_gemmb<true><<<gb.tot, 256, 0, stream>>>(gb);

        // merged aggregates: reaction (p2r + m2r), protein (r2p), molecule (r2m)
        ABatch ab{};
        ab.s[0] = ASeg{cs.offs[0], cs.csr[0], P + 256, 512, bl_ + 0 * HID_,
                       cs.offs[1], cs.csr[1], M + 256, 512, bl_ + 1 * HID_,
                       R, 768, NR_, 0};
        ab.s[1] = ASeg{cs.offs[2], cs.csr[2], R + 256, 768, bl_ + 2 * HID_,
                       nullptr, nullptr, nullptr, 0, nullptr,
                       P, 512, NP2_, AB_R};
        ab.s[2] = ASeg{cs.offs[3], cs.csr[3], R + 512, 768, bl_ + 3 * HID_,
                       nullptr, nullptr, nullptr, 0, nullptr,
                       M, 512, NM_, AB_R + AB_P};
        ab.b1 = AB_R; ab.b2 = AB_R + AB_P;
        k_aggb<<<AB_R + AB_P + AB_M, 256, 0, stream>>>(ab);
    }

    // ---- finale: reaction proj (bf16-A) + notes projs (f32-A pipelined) + cosine ----
    {
        GBatch g1{};
        g1.s[0] = seg(Rb[1], Bre, ro, bre, 768, OUTD_, NR_, HID_, 1, 0);
        g1.b1 = g1.b2 = g1.tot = MT_R;
        k_gemmb<false><<<g1.tot, 256, 0, stream>>>(g1);
        GBatch g2{};
        g2.s[0] = seg(notes, Bn, pr, bn, EMB_, 384, NR_, EMB_, 3, 0);
        g2.b1 = g2.b2 = g2.tot = MT_R * 3;
        k_gemma<false><<<g2.tot, 256, 0, stream>>>(g2);
    }
    k_cos<<<NR_ / 4, 256, 0, stream>>>(ro, pr, types, out, NR_);
}